// Round 7
// baseline (714.918 us; speedup 1.0000x reference)
//
#include <hip/hip_runtime.h>
#include <cstdint>
#include <cstddef>

// GatedDeltaNet forward, MI355X/gfx950.
// Inputs/outputs are fp32 (reference computes in jnp.float32).
// Pipeline: cast(x,Wqkv,Wz,Wout -> bf16) -> [gemm qkv] [gemm z] [proj b/a (g)]
//           -> conv1d+silu (fp32) -> l2norm q,k
//           -> k_prep (PARALLEL per chunk) -> k_scan (SEQUENTIAL 32 chunks)
//           -> gated RMSNorm*silu(z) (bf16) -> [gemm out -> fp32 d_out].
// R6->R7: k_scan was 95% exposed load latency (13k cy/chunk vs ~900 cy work).
// All chunk inputs are state-independent -> double-banked register prefetch of
// next chunk's Wk/Ul/Pm/Q/gt issued mid-chunk, pinned with sched_barrier(0).

typedef unsigned short ushort_t;
typedef __attribute__((ext_vector_type(8))) __bf16 bf16x8;
typedef __attribute__((ext_vector_type(4))) float f32x4;
typedef __attribute__((ext_vector_type(4))) short short4v;

#define B_   2
#define T_   2048
#define HID_ 2048
#define NK_  8
#define NV_  16
#define HD_  128
#define KD_  1024
#define VD_  2048
#define CD_  4096

__device__ __forceinline__ float b2f(ushort_t u) {
  union { unsigned int i; float f; } v; v.i = ((unsigned int)u) << 16; return v.f;
}
__device__ __forceinline__ ushort_t f2b(float f) {   // RNE bf16 round
  unsigned int x = __builtin_bit_cast(unsigned int, f);
  unsigned int r = x + 0x7fffu + ((x >> 16) & 1u);
  return (ushort_t)(r >> 16);
}

// ---------------------------------------------------------------------------
// fp32 -> bf16 cast (vectorized: 4 elems/thread)
// ---------------------------------------------------------------------------
__global__ __launch_bounds__(256)
void k_cast_bf16(const float* __restrict__ in, ushort_t* __restrict__ out, int n4) {
  const int i = blockIdx.x * 256 + threadIdx.x;
  if (i >= n4) return;
  float4 v = *(const float4*)(in + (size_t)i * 4);
  short4v o;
  o[0] = (short)f2b(v.x); o[1] = (short)f2b(v.y);
  o[2] = (short)f2b(v.z); o[3] = (short)f2b(v.w);
  *(short4v*)(out + (size_t)i * 4) = o;
}

// ---------------------------------------------------------------------------
// GEMM: C[m,n] = sum_k A[m,k] * B[n,k]   (A: MxK row-major bf16, B: NxK bf16)
// m97 structure: 128x128 tile, BK=32, 4 waves, global_load_lds width 16.
// ---------------------------------------------------------------------------
template <typename OutT>
__global__ __launch_bounds__(256)
void k_gemm_bt(const ushort_t* __restrict__ A, const ushort_t* __restrict__ Bw,
               OutT* __restrict__ C, int M, int N, int K) {
  __shared__ alignas(16) ushort_t As[128 * 32];
  __shared__ alignas(16) ushort_t Bs[128 * 32];
  const int tid  = threadIdx.x;
  const int lane = tid & 63;
  const int wave = tid >> 6;
  const int wr = wave >> 1, wc = wave & 1;
  const size_t row0 = (size_t)blockIdx.y * 128;
  const size_t col0 = (size_t)blockIdx.x * 128;

  f32x4 acc[4][4] = {};
  const int fr = lane & 15;            // fragment row/col
  const int ks = (lane >> 4) * 8;      // k-slice within BK=32

  for (int kt = 0; kt < K; kt += 32) {
    __syncthreads();                   // LDS reads of prev tile done
#pragma unroll
    for (int ch = 0; ch < 2; ++ch) {
      const int li  = ch * 256 + tid;  // 16B-unit index, 512 per 8KB tile
      const int row = li >> 2;
      const int cp  = li & 3;
      const ushort_t* ga = A  + (row0 + row) * (size_t)K + kt + cp * 8;
      const ushort_t* gb = Bw + (col0 + row) * (size_t)K + kt + cp * 8;
      ushort_t* la = As + ((li >> 6) << 9);  // wave-uniform 1KB chunk base
      ushort_t* lb = Bs + ((li >> 6) << 9);
      __builtin_amdgcn_global_load_lds(
          (const __attribute__((address_space(1))) unsigned int*)ga,
          (__attribute__((address_space(3))) unsigned int*)la, 16, 0, 0);
      __builtin_amdgcn_global_load_lds(
          (const __attribute__((address_space(1))) unsigned int*)gb,
          (__attribute__((address_space(3))) unsigned int*)lb, 16, 0, 0);
    }
    __syncthreads();                   // vmcnt(0) drained by compiler

    bf16x8 af[4], bfv[4];
#pragma unroll
    for (int m = 0; m < 4; ++m)
      af[m]  = *(const bf16x8*)&As[(wr * 64 + m * 16 + fr) * 32 + ks];
#pragma unroll
    for (int n = 0; n < 4; ++n)
      bfv[n] = *(const bf16x8*)&Bs[(wc * 64 + n * 16 + fr) * 32 + ks];
#pragma unroll
    for (int m = 0; m < 4; ++m)
#pragma unroll
      for (int n = 0; n < 4; ++n)
        acc[m][n] = __builtin_amdgcn_mfma_f32_16x16x32_bf16(af[m], bfv[n], acc[m][n], 0, 0, 0);
  }

  const int r4 = (lane >> 4) * 4;      // C/D: col=lane&15, row=(lane>>4)*4+reg
#pragma unroll
  for (int m = 0; m < 4; ++m)
#pragma unroll
    for (int n = 0; n < 4; ++n)
#pragma unroll
      for (int j = 0; j < 4; ++j) {
        const size_t row = row0 + wr * 64 + m * 16 + r4 + j;
        const size_t col = col0 + wc * 64 + n * 16 + fr;
        if constexpr (sizeof(OutT) == 4)
          C[row * (size_t)N + col] = acc[m][n][j];
        else
          C[row * (size_t)N + col] = (OutT)f2b(acc[m][n][j]);
      }
}

// ---------------------------------------------------------------------------
// b/a projection + activation (fp32 in): beta = sigmoid(x@Wb^T),
// g = -exp(A_log) * softplus(x@Wa^T + dt_bias)   [log-decay, for chunk cumsum]
// ---------------------------------------------------------------------------
__global__ __launch_bounds__(256)
void k_proj_ba(const float* __restrict__ x, const float* __restrict__ Wb,
               const float* __restrict__ Wa, const float* __restrict__ dtb,
               const float* __restrict__ alog,
               float* __restrict__ beta, float* __restrict__ gout) {
  __shared__ float xs[HID_];
  __shared__ float part[32][8];
  const int bt = blockIdx.x, tid = threadIdx.x;
  const float* xr = x + (size_t)bt * HID_;
  *(float4*)&xs[tid * 8]     = *(const float4*)&xr[tid * 8];
  *(float4*)&xs[tid * 8 + 4] = *(const float4*)&xr[tid * 8 + 4];
  __syncthreads();
  const int o = tid >> 3, seg = tid & 7;
  const float* W = (o < 16) ? (Wb + (size_t)o * HID_) : (Wa + (size_t)(o - 16) * HID_);
  float s = 0.f;
  for (int k = seg * 256; k < seg * 256 + 256; k += 4) {
    float4 wv = *(const float4*)&W[k];
    float4 xv = *(const float4*)&xs[k];
    s += wv.x * xv.x + wv.y * xv.y + wv.z * xv.z + wv.w * xv.w;
  }
  part[o][seg] = s;
  __syncthreads();
  if (tid < 32) {
    float tsum = 0.f;
#pragma unroll
    for (int i = 0; i < 8; ++i) tsum += part[tid][i];
    if (tid < 16) {
      beta[(size_t)bt * NV_ + tid] = 1.f / (1.f + expf(-tsum));
    } else {
      const int h = tid - 16;
      float aa = tsum + dtb[h];
      float sp = (aa > 20.f) ? aa : log1pf(expf(aa));
      gout[(size_t)bt * NV_ + h] = -expf(alog[h]) * sp;
    }
  }
}

// ---------------------------------------------------------------------------
// Depthwise causal conv1d (K=4, left zero-pad) + silu, bf16 in -> fp32 out.
// ---------------------------------------------------------------------------
__global__ __launch_bounds__(256)
void k_conv_silu(const ushort_t* __restrict__ qkv, const float* __restrict__ cw,
                 float* __restrict__ act) {
  const unsigned idx = blockIdx.x * 256u + threadIdx.x;  // B*T*CD/4 total
  const unsigned c4  = idx & (CD_ / 4 - 1);
  const unsigned bt  = idx >> 10;                        // / (CD_/4)
  const int t = bt & (T_ - 1);
  const int c = c4 * 4;
  const ushort_t* rowp = qkv + (size_t)bt * CD_ + c;
  float wf[4][4];
#pragma unroll
  for (int i = 0; i < 4; ++i) {
    float4 w = *(const float4*)&cw[(c + i) * 4];
    wf[i][0] = w.x; wf[i][1] = w.y; wf[i][2] = w.z; wf[i][3] = w.w;
  }
  float a[4] = {0.f, 0.f, 0.f, 0.f};
#pragma unroll
  for (int j = 0; j < 4; ++j) {
    const int tt = t - 3 + j;
    if (tt >= 0) {
      short4v iv = *(const short4v*)(rowp + ((ptrdiff_t)j - 3) * CD_);
#pragma unroll
      for (int i = 0; i < 4; ++i) a[i] += b2f((ushort_t)iv[i]) * wf[i][j];
    }
  }
  float4 o;
  o.x = a[0] / (1.f + expf(-a[0]));
  o.y = a[1] / (1.f + expf(-a[1]));
  o.z = a[2] / (1.f + expf(-a[2]));
  o.w = a[3] / (1.f + expf(-a[3]));
  *(float4*)(act + (size_t)bt * CD_ + c) = o;
}

// ---------------------------------------------------------------------------
// L2-normalize q (with HD^-1/2 scale) and k rows in-place (fp32). Wave per row.
// ---------------------------------------------------------------------------
__global__ __launch_bounds__(256)
void k_l2norm_qk(float* __restrict__ act) {
  const int row  = blockIdx.x * 4 + (threadIdx.x >> 6);  // B*T*16 rows
  const int lane = threadIdx.x & 63;
  const int bt = row >> 4, s = row & 15;
  float* p = act + (size_t)bt * CD_ + (s < 8 ? s * HD_ : KD_ + (s - 8) * HD_);
  float2 v = *(float2*)&p[lane * 2];
  float ss = v.x * v.x + v.y * v.y;
#pragma unroll
  for (int m = 1; m < 64; m <<= 1) ss += __shfl_xor(ss, m);
  float scale = 1.f / fmaxf(sqrtf(ss), 1e-12f);
  if (s < 8) scale *= 0.08838834764831845f;  // HD^-0.5
  v.x *= scale; v.y *= scale;
  *(float2*)&p[lane * 2] = v;
}

// ---------------------------------------------------------------------------
__device__ __forceinline__ bf16x8 cvt8f(const float* p) {
  float4 a = *(const float4*)p;
  float4 b = *(const float4*)(p + 4);
  bf16x8 o;
  o[0] = (__bf16)a.x; o[1] = (__bf16)a.y; o[2] = (__bf16)a.z; o[3] = (__bf16)a.w;
  o[4] = (__bf16)b.x; o[5] = (__bf16)b.y; o[6] = (__bf16)b.z; o[7] = (__bf16)b.w;
  return o;
}
__device__ __forceinline__ bf16x8 cvt8r(float4 a, float4 b) {
  bf16x8 o;
  o[0] = (__bf16)a.x; o[1] = (__bf16)a.y; o[2] = (__bf16)a.z; o[3] = (__bf16)a.w;
  o[4] = (__bf16)b.x; o[5] = (__bf16)b.y; o[6] = (__bf16)b.z; o[7] = (__bf16)b.w;
  return o;
}

// ---------------------------------------------------------------------------
// k_prep: per-chunk parallel precompute. grid = B*NV*NC = 1024. (unchanged R6)
// ---------------------------------------------------------------------------
__global__ __launch_bounds__(256, 1)
void k_prep(const float* __restrict__ act, const float* __restrict__ gB,
            const float* __restrict__ betaB,
            ushort_t* __restrict__ WkG, ushort_t* __restrict__ UlG,
            ushort_t* __restrict__ PmG, ushort_t* __restrict__ kTG,
            float* __restrict__ gtG) {
  __shared__ __bf16 Kl[64][136];
  __shared__ __bf16 AbL[64][40];
  __shared__ __bf16 AbH[32][33];
  __shared__ __bf16 Xl[64][256];
  __shared__ float gc[65], Et[65], Rt[65], bts[64], geT[64];

  const int wg = blockIdx.x;                 // ((b*16+h)*32 + c)
  const int c = wg & 31, h = (wg >> 5) & 15, b = wg >> 9;
  const int hq = h >> 1, t0 = c * 64;
  const int tid = threadIdx.x, lane = tid & 63, wave = tid >> 6;
  const int l15 = lane & 15, kcol0 = (lane >> 4) * 8, rrow = (lane >> 4) * 4;
  const size_t bhc = (size_t)wg;

  const float* baseQ = act + (size_t)b * T_ * CD_ + hq * HD_;
  const float* baseK = baseQ + KD_;

  if (tid < 64) {
    float g = gB[((size_t)b * T_ + t0 + tid) * NV_ + h];
    bts[tid] = betaB[((size_t)b * T_ + t0 + tid) * NV_ + h];
#pragma unroll
    for (int o = 1; o < 64; o <<= 1) {
      float up = __shfl_up(g, (unsigned)o);
      if (tid >= o) g += up;
    }
    gc[tid + 1] = g;
    if (tid == 0) gc[0] = 0.f;
  }
  __syncthreads();
  if (tid < 65) {
    float gm = gc[32];
    Et[tid] = __expf(gc[tid] - gm);
    Rt[tid] = __expf(gm - gc[tid]);
  }
  if (tid < 64) {
    geT[tid] = bts[tid] * __expf(gc[tid + 1]);
    gtG[bhc * 64 + tid] = gc[tid + 1];
  }
  {
    const int t = tid >> 2, d0 = (tid & 3) * 32;
    const float* src = baseK + (size_t)(t0 + t) * CD_ + d0;
#pragma unroll
    for (int j = 0; j < 8; ++j) {
      float4 v = *(const float4*)(src + j * 4);
      Kl[t][d0 + j * 4 + 0] = (__bf16)v.x;
      Kl[t][d0 + j * 4 + 1] = (__bf16)v.y;
      Kl[t][d0 + j * 4 + 2] = (__bf16)v.z;
      Kl[t][d0 + j * 4 + 3] = (__bf16)v.w;
    }
  }
  __syncthreads();

  {
    bf16x8 kf[4], qf[4];
#pragma unroll
    for (int kk = 0; kk < 4; ++kk) {
      kf[kk] = *(const bf16x8*)&Kl[16 * wave + l15][kk * 32 + kcol0];
      qf[kk] = cvt8f(baseQ + (size_t)(t0 + 16 * wave + l15) * CD_ + kk * 32 + kcol0);
    }
#pragma unroll
    for (int st = 0; st < 4; ++st) {
      f32x4 accA = {}, accP = {};
#pragma unroll
      for (int kk = 0; kk < 4; ++kk) {
        bf16x8 bfr = *(const bf16x8*)&Kl[st * 16 + l15][kk * 32 + kcol0];
        accA = __builtin_amdgcn_mfma_f32_16x16x32_bf16(kf[kk], bfr, accA, 0, 0, 0);
        accP = __builtin_amdgcn_mfma_f32_16x16x32_bf16(qf[kk], bfr, accP, 0, 0, 0);
      }
      const int scol = st * 16 + l15;
#pragma unroll
      for (int r = 0; r < 4; ++r) {
        const int t = 16 * wave + rrow + r;
        const float sc = Et[t + 1] * Rt[scol + 1];
        if (scol < t) {
          const float av = -bts[t] * sc * accA[r];
          if (scol < 32) AbL[t][scol] = (__bf16)av;
          else           AbH[t - 32][scol - 32] = (__bf16)av;
        }
        PmG[bhc * 4608 + (size_t)t * 72 + scol] =
            (scol <= t) ? f2b(sc * accP[r]) : (ushort_t)0;
      }
    }
  }
  if ((h & 1) == 0) {
    const size_t kto = (((size_t)b * 8 + hq) * 32 + c) * (128 * 72);
    const int d = tid >> 1, t8 = (tid & 1) * 32;
#pragma unroll
    for (int i8 = 0; i8 < 4; ++i8) {
      bf16x8 tmp;
#pragma unroll
      for (int jj = 0; jj < 8; ++jj) tmp[jj] = Kl[t8 + i8 * 8 + jj][d];
      *(bf16x8*)(void*)(kTG + kto + (size_t)d * 72 + t8 + i8 * 8) = tmp;
    }
  }
  __syncthreads();

  {
    float r1[32], r2[32];
    if (tid < 128) {
      const int d = tid;
#pragma unroll
      for (int t = 0; t < 32; ++t) r1[t] = geT[t] * (float)Kl[t][d];
#pragma unroll
      for (int t = 0; t < 32; ++t) r2[t] = geT[32 + t] * (float)Kl[32 + t][d];
    } else {
      const int j = tid - 128;
      const float* vsrc = act + ((size_t)b * T_ + t0) * CD_ + 2 * KD_ + h * HD_ + j;
#pragma unroll
      for (int t = 0; t < 32; ++t) r1[t] = bts[t] * vsrc[(size_t)t * CD_];
#pragma unroll
      for (int t = 0; t < 32; ++t) r2[t] = bts[32 + t] * vsrc[(size_t)(32 + t) * CD_];
    }
    float u1[32];
#pragma unroll
    for (int j = 0; j < 32; ++j) {
      float a = r1[j];
#pragma unroll
      for (int i = 0; i < j; ++i) a += (float)AbL[j][i] * u1[i];
      u1[j] = a;
      Xl[j][tid] = (__bf16)a;
    }
#pragma unroll
    for (int t2 = 0; t2 < 32; ++t2) {
      float a = r2[t2];
#pragma unroll
      for (int i = 0; i < 32; ++i) a += (float)AbL[32 + t2][i] * u1[i];
      r2[t2] = a;
    }
    float u2[32];
#pragma unroll
    for (int j = 0; j < 32; ++j) {
      float a = r2[j];
#pragma unroll
      for (int i = 0; i < j; ++i) a += (float)AbH[j][i] * u2[i];
      u2[j] = a;
      Xl[32 + j][tid] = (__bf16)a;
    }
  }
  __syncthreads();

#pragma unroll
  for (int kck = 0; kck < 4; ++kck) {
    const int q = tid + kck * 256;             // 0..1023
    const int t = q >> 4, d0 = (q & 15) * 8;
    uint4 v = *(const uint4*)&Xl[t][d0];
    v.x ^= 0x80008000u; v.y ^= 0x80008000u; v.z ^= 0x80008000u; v.w ^= 0x80008000u;
    *(uint4*)(void*)(WkG + bhc * (64 * 136) + (size_t)t * 136 + d0) = v;
    uint4 w = *(const uint4*)&Xl[t][128 + d0];
    *(uint4*)(void*)(UlG + bhc * (64 * 136) + (size_t)t * 136 + d0) = w;
  }
}

// ---------------------------------------------------------------------------
// k_scan: sequential inter-chunk state recurrence + fused output. grid = B*NV.
// R7: double-banked register prefetch of next chunk's state-independent inputs
// (Wk frags, Ul, Pm, raw Q, gt), issued mid-chunk, pinned by sched_barrier(0).
// ---------------------------------------------------------------------------
__global__ __launch_bounds__(256, 1)
void k_scan(const float* __restrict__ act,
            const ushort_t* __restrict__ WkG, const ushort_t* __restrict__ UlG,
            const ushort_t* __restrict__ PmG, const ushort_t* __restrict__ kTG,
            const float* __restrict__ gtG, float* __restrict__ ob) {
  __shared__ __bf16 S16[128][136];   // 34816 B
  __shared__ __bf16 uTl[128][72];    // 18432 B
  __shared__ float gam[64], esc[64];

  const int wg = blockIdx.x;                 // b*16 + h
  const int h = wg & 15, b = wg >> 4, hq = h >> 1;
  const int tid = threadIdx.x, lane = tid & 63, wave = tid >> 6;
  const int l15 = lane & 15, kcol0 = (lane >> 4) * 8, rrow = (lane >> 4) * 4;

  f32x4 s_acc[2][8] = {};    // j-tiles {2w,2w+1} x 8 d-tiles

  // prefetch banks (A/B), explicit names (no runtime indexing)
  bf16x8 waA[4], waB[4], paA[2], paB[2];
  ushort_t uvA[32], uvB[32];
  float4 qaA[8], qaB[8];
  float gtA, gtB;

#define LOADNEXT(BK, CN) {                                                    \
    const int cn_ = ((CN) < 32) ? (CN) : 31;                                  \
    const size_t bhcn_ = (size_t)wg * 32 + cn_;                               \
    const ushort_t* WkR_ = WkG + bhcn_ * (64 * 136);                          \
    const ushort_t* UlR_ = UlG + bhcn_ * (64 * 136);                          \
    const ushort_t* PmR_ = PmG + bhcn_ * 4608;                                \
    _Pragma("unroll") for (int kk = 0; kk < 4; ++kk)                          \
      wa##BK[kk] = *(const bf16x8*)(const void*)                              \
          (WkR_ + (size_t)(16 * wave + l15) * 136 + kk * 32 + kcol0);         \
    _Pragma("unroll") for (int jt = 0; jt < 8; ++jt)                          \
      _Pragma("unroll") for (int r = 0; r < 4; ++r)                           \
        uv##BK[jt * 4 + r] =                                                  \
            UlR_[(size_t)(16 * wave + rrow + r) * 136 + jt * 16 + l15];       \
    _Pragma("unroll") for (int ks = 0; ks < 2; ++ks)                          \
      pa##BK[ks] = *(const bf16x8*)(const void*)                              \
          (PmR_ + (size_t)(16 * wave + l15) * 72 + ks * 32 + kcol0);          \
    _Pragma("unroll") for (int kk = 0; kk < 4; ++kk) {                        \
      const float* qp_ = act + ((size_t)b * T_ + cn_ * 64 + 16 * wave + l15) * CD_ \
                         + hq * HD_ + kk * 32 + kcol0;                        \
      qa##BK[2 * kk]     = *(const float4*)qp_;                               \
      qa##BK[2 * kk + 1] = *(const float4*)(qp_ + 4);                         \
    }                                                                         \
    gt##BK = gtG[bhcn_ * 64 + (tid & 63)];                                    \
  }

#define STEP(BK, OBK, C) {                                                    \
    const int t0g_ = (C) * 64;                                                \
    const size_t bhc_ = (size_t)wg * 32 + (C);                                \
    const ushort_t* kTR_ = kTG + (((size_t)b * 8 + hq) * 32 + (C)) * (128 * 72); \
    /* tables from prefetched gt */                                           \
    {                                                                         \
      const float gv_ = gt##BK;                                               \
      const float gC_ = __shfl(gv_, 63);                                      \
      if (tid < 64) { gam[tid] = __expf(gv_); esc[tid] = __expf(gC_ - gv_); } \
    }                                                                         \
    /* S16 <- bf16(S) */                                                      \
    _Pragma("unroll") for (int jt2 = 0; jt2 < 2; ++jt2)                       \
      _Pragma("unroll") for (int dt = 0; dt < 8; ++dt)                        \
        _Pragma("unroll") for (int r = 0; r < 4; ++r)                         \
          S16[(2 * wave + jt2) * 16 + rrow + r][dt * 16 + l15] =              \
              (__bf16)s_acc[jt2][dt][r];                                      \
    __syncthreads();                                                          \
    /* u-phase: u = Uloc + (-Wk)@S */                                         \
    f32x4 au_[8];                                                             \
    _Pragma("unroll") for (int jt = 0; jt < 8; ++jt)                          \
      _Pragma("unroll") for (int r = 0; r < 4; ++r)                           \
        au_[jt][r] = b2f(uv##BK[jt * 4 + r]);                                 \
    _Pragma("unroll") for (int kk = 0; kk < 4; ++kk)                          \
      _Pragma("unroll") for (int jt = 0; jt < 8; ++jt) {                      \
        bf16x8 sb_ = *(const bf16x8*)&S16[jt * 16 + l15][kk * 32 + kcol0];    \
        au_[jt] = __builtin_amdgcn_mfma_f32_16x16x32_bf16(wa##BK[kk], sb_, au_[jt], 0, 0, 0); \
      }                                                                       \
    _Pragma("unroll") for (int jt = 0; jt < 8; ++jt)                          \
      _Pragma("unroll") for (int r = 0; r < 4; ++r)                           \
        uTl[jt * 16 + l15][16 * wave + rrow + r] = (__bf16)au_[jt][r];        \
    /* issue next-chunk prefetch, pin with sched_barrier */                   \
    LOADNEXT(OBK, (C) + 1)                                                    \
    __builtin_amdgcn_sched_barrier(0);                                        \
    __syncthreads();                                                          \
    /* o-phase: o = gam*Q@S + Pm@u */                                         \
    f32x4 qs_[8] = {}, o2_[8] = {};                                           \
    _Pragma("unroll") for (int kk = 0; kk < 4; ++kk) {                        \
      bf16x8 qa_ = cvt8r(qa##BK[2 * kk], qa##BK[2 * kk + 1]);                 \
      _Pragma("unroll") for (int jt = 0; jt < 8; ++jt) {                      \
        bf16x8 sb_ = *(const bf16x8*)&S16[jt * 16 + l15][kk * 32 + kcol0];    \
        qs_[jt] = __builtin_amdgcn_mfma_f32_16x16x32_bf16(qa_, sb_, qs_[jt], 0, 0, 0); \
      }                                                                       \
    }                                                                         \
    _Pragma("unroll") for (int ks = 0; ks < 2; ++ks) {                        \
      _Pragma("unroll") for (int jt = 0; jt < 8; ++jt) {                      \
        bf16x8 ub_ = *(const bf16x8*)&uTl[jt * 16 + l15][ks * 32 + kcol0];    \
        o2_[jt] = __builtin_amdgcn_mfma_f32_16x16x32_bf16(pa##BK[ks], ub_, o2_[jt], 0, 0, 0); \
      }                                                                       \
    }                                                                         \
    _Pragma("unroll") for (int jt = 0; jt < 8; ++jt)                          \
      _Pragma("unroll") for (int r = 0; r < 4; ++r) {                         \
        const int t_ = 16 * wave + rrow + r;                                  \
        ob[(((size_t)b * T_ + t0g_ + t_) * NV_ + h) * HD_ + jt * 16 + l15] =  \
            gam[t_] * qs_[jt][r] + o2_[jt][r];                                \
      }                                                                       \
    /* S-update: S = gam[63]*S + K^T (esc*u) */                               \
    const float gCe_ = gam[63];                                               \
    _Pragma("unroll") for (int jt2 = 0; jt2 < 2; ++jt2)                       \
      _Pragma("unroll") for (int dt = 0; dt < 8; ++dt)                        \
        _Pragma("unroll") for (int r = 0; r < 4; ++r) s_acc[jt2][dt][r] *= gCe_; \
    _Pragma("unroll") for (int ks = 0; ks < 2; ++ks) {                        \
      bf16x8 ua_[2];                                                          \
      _Pragma("unroll") for (int jt2 = 0; jt2 < 2; ++jt2) {                   \
        bf16x8 raw_ = *(const bf16x8*)&uTl[(2 * wave + jt2) * 16 + l15][ks * 32 + kcol0]; \
        _Pragma("unroll") for (int e = 0; e < 8; ++e)                         \
          ua_[jt2][e] = (__bf16)((float)raw_[e] * esc[ks * 32 + kcol0 + e]);  \
      }                                                                       \
      _Pragma("unroll") for (int dt = 0; dt < 8; ++dt) {                      \
        bf16x8 kb_ = *(const bf16x8*)(const void*)                            \
            (kTR_ + (size_t)(dt * 16 + l15) * 72 + ks * 32 + kcol0);          \
        s_acc[0][dt] = __builtin_amdgcn_mfma_f32_16x16x32_bf16(ua_[0], kb_, s_acc[0][dt], 0, 0, 0); \
        s_acc[1][dt] = __builtin_amdgcn_mfma_f32_16x16x32_bf16(ua_[1], kb_, s_acc[1][dt], 0, 0, 0); \
      }                                                                       \
    }                                                                         \
    __syncthreads();                                                          \
  }

  LOADNEXT(A, 0)
  for (int cc = 0; cc < 16; ++cc) {
    STEP(A, B, cc * 2)
    STEP(B, A, cc * 2 + 1)
  }
#undef LOADNEXT
#undef STEP
}

// ---------------------------------------------------------------------------
// Gated RMSNorm: out = (o/rms(o)) * norm_w * silu(z); fp32 o, bf16 z,
// fp32 norm_w -> bf16 out (final GEMM operand).
// ---------------------------------------------------------------------------
__global__ __launch_bounds__(256)
void k_gate_rms(const float* __restrict__ ob, const ushort_t* __restrict__ z,
                const float* __restrict__ nw, ushort_t* __restrict__ og) {
  const int row  = blockIdx.x * 4 + (threadIdx.x >> 6);  // B*T*NV rows
  const int lane = threadIdx.x & 63;
  const float* op = ob + (size_t)row * HD_;
  float2 v = *(const float2*)&op[lane * 2];
  float ss = v.x * v.x + v.y * v.y;
#pragma unroll
  for (int m = 1; m < 64; m <<= 1) ss += __shfl_xor(ss, m);
  const float r = 1.f / sqrtf(ss * (1.f / HD_) + 1e-6f);
  unsigned int zz = *(const unsigned int*)&z[(size_t)row * HD_ + lane * 2];
  float z0 = b2f((ushort_t)(zz & 0xffffu));
  float z1 = b2f((ushort_t)(zz >> 16));
  float2 w = *(const float2*)&nw[lane * 2];
  float g0 = z0 / (1.f + expf(-z0));
  float g1 = z1 / (1.f + expf(-z1));
  unsigned int pack = (unsigned int)f2b(v.x * r * w.x * g0)
                    | ((unsigned int)f2b(v.y * r * w.y * g1) << 16);
  *(unsigned int*)&og[(size_t)row * HD_ + lane * 2] = pack;
}

// ---------------------------------------------------------------------------
extern "C" void kernel_launch(void* const* d_in, const int* in_sizes, int n_in,
                              void* d_out, int out_size, void* d_ws, size_t ws_size,
                              hipStream_t stream) {
  const float* x    = (const float*)d_in[0];
  const float* Wqkv = (const float*)d_in[1];
  const float* Wz   = (const float*)d_in[2];
  const float* Wb   = (const float*)d_in[3];
  const float* Wa   = (const float*)d_in[4];
  const float* cw   = (const float*)d_in[5];
  const float* dtb  = (const float*)d_in[6];
  const float* alog = (const float*)d_in[7];
  const float* nw   = (const float*)d_in[8];
  const float* Wout = (const float*)d_in[9];

  char* p = (char*)d_ws;
  ushort_t* qkv_raw = (ushort_t*)p; p += (size_t)B_ * T_ * CD_ * 2;       // 33.5 MB
  ushort_t* zbuf    = (ushort_t*)p; p += (size_t)B_ * T_ * VD_ * 2;       // 16.8 MB
  char*     actBase = p;
  float*    act     = (float*)p;    p += (size_t)B_ * T_ * CD_ * 4;       // 67.1 MB
  float*    betaB   = (float*)p;    p += (size_t)B_ * T_ * NV_ * 4;
  float*    gBuf    = (float*)p;    p += (size_t)B_ * T_ * NV_ * 4;
  float*    obuf    = (float*)p;    p += (size_t)B_ * T_ * NV_ * HD_ * 4; // 33.5 MB
  ushort_t* WoutB   = (ushort_t*)p; p += (size_t)HID_ * VD_ * 2;          // 8.4 MB
  ushort_t* UlG     = (ushort_t*)p; p += (size_t)1024 * 64 * 136 * 2;     // 17.8 MB
  ushort_t* PmG     = (ushort_t*)p; p += (size_t)1024 * 64 * 72 * 2;      //  9.4 MB
  // overlays in qkv_raw region (dead after conv; outg written after k_scan):
  ushort_t* WkG = qkv_raw;                                                // 17.8 MB
  ushort_t* kTG = (ushort_t*)((char*)qkv_raw + 17825792);                 //  9.4 MB
  float*    gtG = (float*)((char*)qkv_raw + 27262976);                    //  0.26 MB
  // bf16 cast buffers aliased into act region (dead before conv writes act):
  ushort_t* xB    = (ushort_t*)(actBase);                                 // 16.8 MB
  ushort_t* WqkvB = (ushort_t*)(actBase + (size_t)B_ * T_ * HID_ * 2);    // 16.8 MB
  ushort_t* WzB   = (ushort_t*)(actBase + (size_t)B_ * T_ * HID_ * 2
                                        + (size_t)CD_ * HID_ * 2);        // 8.4 MB
  ushort_t* outg  = qkv_raw;        // reuse again after k_scan

  const int M = B_ * T_;  // 4096

  hipLaunchKernelGGL(k_cast_bf16, dim3(M * HID_ / 4 / 256), dim3(256), 0, stream,
                     x, xB, M * HID_ / 4);
  hipLaunchKernelGGL(k_cast_bf16, dim3(CD_ * HID_ / 4 / 256), dim3(256), 0, stream,
                     Wqkv, WqkvB, CD_ * HID_ / 4);
  hipLaunchKernelGGL(k_cast_bf16, dim3(VD_ * HID_ / 4 / 256), dim3(256), 0, stream,
                     Wz, WzB, VD_ * HID_ / 4);
  hipLaunchKernelGGL(k_cast_bf16, dim3(HID_ * VD_ / 4 / 256), dim3(256), 0, stream,
                     Wout, WoutB, HID_ * VD_ / 4);

  hipLaunchKernelGGL(k_gemm_bt<ushort_t>, dim3(CD_ / 128, M / 128), dim3(256), 0, stream,
                     xB, WqkvB, qkv_raw, M, CD_, HID_);
  hipLaunchKernelGGL(k_gemm_bt<ushort_t>, dim3(VD_ / 128, M / 128), dim3(256), 0, stream,
                     xB, WzB, zbuf, M, VD_, HID_);
  hipLaunchKernelGGL(k_proj_ba, dim3(M), dim3(256), 0, stream,
                     x, Wb, Wa, dtb, alog, betaB, gBuf);
  hipLaunchKernelGGL(k_conv_silu, dim3(M * CD_ / 4 / 256), dim3(256), 0, stream,
                     qkv_raw, cw, act);
  hipLaunchKernelGGL(k_l2norm_qk, dim3(M * 16 / 4), dim3(256), 0, stream, act);
  hipLaunchKernelGGL(k_prep, dim3(B_ * NV_ * 32), dim3(256), 0, stream,
                     act, gBuf, betaB, WkG, UlG, PmG, kTG, gtG);
  hipLaunchKernelGGL(k_scan, dim3(B_ * NV_), dim3(256), 0, stream,
                     act, WkG, UlG, PmG, kTG, gtG, obuf);
  hipLaunchKernelGGL(k_gate_rms, dim3(M * NV_ / 4), dim3(256), 0, stream,
                     obuf, zbuf, nw, outg);
  hipLaunchKernelGGL(k_gemm_bt<float>, dim3(HID_ / 128, M / 128), dim3(256), 0, stream,
                     outg, WoutB, (float*)d_out, M, HID_, VD_);
}

// Round 8
// 637.672 us; speedup vs baseline: 1.1211x; 1.1211x over previous
//
#include <hip/hip_runtime.h>
#include <cstdint>
#include <cstddef>

// GatedDeltaNet forward, MI355X/gfx950.
// Inputs/outputs are fp32 (reference computes in jnp.float32).
// Pipeline: cast(x,Wqkv,Wz,Wout -> bf16) -> [gemm256 qkv] [gemm256 z] [proj b/a]
//           -> conv1d+silu (fp32) -> l2norm q,k
//           -> k_prep (PARALLEL per chunk) -> k_scan (SEQUENTIAL, R6 version)
//           -> gated RMSNorm*silu(z) (bf16) -> [gemm256 out -> fp32 d_out].
// R8: k_scan reverted to R6 (R7 reg-prefetch regressed). GEMMs upgraded to
// 256x256/BK=64/8-wave with counted vmcnt(8) pipeline (3 half-tiles in flight,
// never drain-0 in loop), raw s_barrier, T2 swizzle (global-source side +
// ds_read side), setprio around MFMA, bijective XCD swizzle.

typedef unsigned short ushort_t;
typedef __attribute__((ext_vector_type(8))) __bf16 bf16x8;
typedef __attribute__((ext_vector_type(4))) float f32x4;
typedef __attribute__((ext_vector_type(4))) short short4v;

#define B_   2
#define T_   2048
#define HID_ 2048
#define NK_  8
#define NV_  16
#define HD_  128
#define KD_  1024
#define VD_  2048
#define CD_  4096

__device__ __forceinline__ float b2f(ushort_t u) {
  union { unsigned int i; float f; } v; v.i = ((unsigned int)u) << 16; return v.f;
}
__device__ __forceinline__ ushort_t f2b(float f) {   // RNE bf16 round
  unsigned int x = __builtin_bit_cast(unsigned int, f);
  unsigned int r = x + 0x7fffu + ((x >> 16) & 1u);
  return (ushort_t)(r >> 16);
}

// ---------------------------------------------------------------------------
// fp32 -> bf16 cast (vectorized: 4 elems/thread)
// ---------------------------------------------------------------------------
__global__ __launch_bounds__(256)
void k_cast_bf16(const float* __restrict__ in, ushort_t* __restrict__ out, int n4) {
  const int i = blockIdx.x * 256 + threadIdx.x;
  if (i >= n4) return;
  float4 v = *(const float4*)(in + (size_t)i * 4);
  short4v o;
  o[0] = (short)f2b(v.x); o[1] = (short)f2b(v.y);
  o[2] = (short)f2b(v.z); o[3] = (short)f2b(v.w);
  *(short4v*)(out + (size_t)i * 4) = o;
}

// ---------------------------------------------------------------------------
// GEMM 256x256, BK=64, 8 waves (512 thr), counted-vmcnt pipeline.
// C[m,n] = sum_k A[m,k]*B[n,k]; A MxK, B NxK row-major bf16.
// LDS: [buf 2][op A/B][Khalf 2][256 rows x 32 k] = 128 KB.
// Swizzle: byte ^= ((row&3)<<4) within each 64B row — applied on the GLOBAL
// source of global_load_lds (linear LDS dest) and on ds_read addresses.
// Schedule per K-tile (2 phases, half = 32 k):
//   phase h: vmcnt(8); s_barrier; ds_read 12 frags (half h);
//            stage next needed half-tile (4 gload_lds); setprio(1); 32 MFMA.
// Half-tile staged 2 phases before use; vmcnt(8) leaves the 2 newest
// half-stages (8 loads) in flight — never drains to 0 in the loop.
// ---------------------------------------------------------------------------
template <typename OutT>
__global__ __launch_bounds__(512, 2)
void k_gemm256(const ushort_t* __restrict__ A, const ushort_t* __restrict__ Bw,
               OutT* __restrict__ C, int M, int N, int K) {
  __shared__ alignas(16) ushort_t lds[2][2][2][8192];   // 128 KB

  const int tid = threadIdx.x;
  const int lane = tid & 63, wave = tid >> 6;
  const int wm = wave >> 2, wc = wave & 3;
  const int l15 = lane & 15;
  const int ks16 = (lane >> 4) * 16;      // byte offset of k-slice in 64B row
  const int r4 = (lane >> 4) * 4;
  const int nkt = K >> 6;

  // bijective XCD swizzle (m204) over 1D grid, then decompose
  const int nwg = gridDim.x;
  const int q8 = nwg >> 3, r8 = nwg & 7;
  const int xcd = blockIdx.x & 7, idx8 = blockIdx.x >> 3;
  const int s = (xcd < r8) ? (xcd * (q8 + 1) + idx8)
                           : (r8 * (q8 + 1) + (xcd - r8) * q8 + idx8);
  const int nbx = N >> 8;
  const size_t row0 = (size_t)(s / nbx) * 256;
  const size_t col0 = (size_t)(s % nbx) * 256;

  // stage one half-tile (A and B) of K-tile KT, K-half HALF, into buffer BUF.
  // Per thread: 2 rounds x {A,B} = 4 gload_lds of 16B. Linear LDS dest;
  // inverse swizzle on the global source column.
#define STAGE4(BUF, HALF, KT) {                                               \
    const int kt_ = ((KT) < nkt) ? (KT) : (nkt - 1);                          \
    const int kb_ = kt_ * 64 + (HALF) * 32;                                   \
    _Pragma("unroll") for (int r_ = 0; r_ < 2; ++r_) {                        \
      const int wb_ = r_ * 8192 + wave * 1024;                                \
      const int o_  = wb_ + lane * 16;                                        \
      const int row_ = o_ >> 6;                                               \
      const int src_ = (o_ & 63) ^ ((row_ & 3) << 4);                         \
      const ushort_t* ga_ = A  + (row0 + row_) * (size_t)K + kb_ + (src_ >> 1); \
      const ushort_t* gb_ = Bw + (col0 + row_) * (size_t)K + kb_ + (src_ >> 1); \
      __builtin_amdgcn_global_load_lds(                                       \
          (const __attribute__((address_space(1))) unsigned int*)ga_,         \
          (__attribute__((address_space(3))) unsigned int*)                   \
              (&lds[BUF][0][HALF][0] + (wb_ >> 1)), 16, 0, 0);                \
      __builtin_amdgcn_global_load_lds(                                       \
          (const __attribute__((address_space(1))) unsigned int*)gb_,         \
          (__attribute__((address_space(3))) unsigned int*)                   \
              (&lds[BUF][1][HALF][0] + (wb_ >> 1)), 16, 0, 0);                \
    }                                                                         \
  }

#define RD(BUF, OP, HALF, ROW)                                                \
  (*(const bf16x8*)((const char*)&lds[BUF][OP][HALF][0] +                     \
                    (((ROW) * 64 + ks16) ^ (((ROW) & 3) << 4))))

  f32x4 acc[8][4] = {};

  // prologue: tile0 both halves + tile1 half0  (12 loads/thread in flight)
  STAGE4(0, 0, 0)
  STAGE4(0, 1, 0)
  STAGE4(1, 0, 1)

  for (int kt = 0; kt < nkt; ++kt) {
    const int cb = kt & 1, nb = cb ^ 1;

    // ---- phase A (K-half 0) ----
    asm volatile("s_waitcnt vmcnt(8)" ::: "memory");
    __builtin_amdgcn_s_barrier();
    {
      bf16x8 af[8], bfr[4];
#pragma unroll
      for (int mf = 0; mf < 8; ++mf) af[mf] = RD(cb, 0, 0, wm * 128 + mf * 16 + l15);
#pragma unroll
      for (int nf = 0; nf < 4; ++nf) bfr[nf] = RD(cb, 1, 0, wc * 64 + nf * 16 + l15);
      STAGE4(nb, 1, kt + 1)        // (kt+1).h1 -> other buf (its h1 was read last phase)
      __builtin_amdgcn_s_setprio(1);
#pragma unroll
      for (int mf = 0; mf < 8; ++mf)
#pragma unroll
        for (int nf = 0; nf < 4; ++nf)
          acc[mf][nf] = __builtin_amdgcn_mfma_f32_16x16x32_bf16(af[mf], bfr[nf], acc[mf][nf], 0, 0, 0);
      __builtin_amdgcn_s_setprio(0);
    }

    // ---- phase B (K-half 1) ----
    asm volatile("s_waitcnt vmcnt(8)" ::: "memory");
    __builtin_amdgcn_s_barrier();
    {
      bf16x8 af[8], bfr[4];
#pragma unroll
      for (int mf = 0; mf < 8; ++mf) af[mf] = RD(cb, 0, 1, wm * 128 + mf * 16 + l15);
#pragma unroll
      for (int nf = 0; nf < 4; ++nf) bfr[nf] = RD(cb, 1, 1, wc * 64 + nf * 16 + l15);
      STAGE4(cb, 0, kt + 2)        // (kt+2).h0 -> current buf h0 (read in phase A)
      __builtin_amdgcn_s_setprio(1);
#pragma unroll
      for (int mf = 0; mf < 8; ++mf)
#pragma unroll
        for (int nf = 0; nf < 4; ++nf)
          acc[mf][nf] = __builtin_amdgcn_mfma_f32_16x16x32_bf16(af[mf], bfr[nf], acc[mf][nf], 0, 0, 0);
      __builtin_amdgcn_s_setprio(0);
    }
  }
#undef STAGE4
#undef RD

  // epilogue: C write. D row <- first operand (r4+j), D col <- second (l15).
#pragma unroll
  for (int mf = 0; mf < 8; ++mf)
#pragma unroll
    for (int nf = 0; nf < 4; ++nf)
#pragma unroll
      for (int j = 0; j < 4; ++j) {
        const size_t row = row0 + wm * 128 + mf * 16 + r4 + j;
        const size_t col = col0 + wc * 64 + nf * 16 + l15;
        if constexpr (sizeof(OutT) == 4)
          C[row * (size_t)N + col] = acc[mf][nf][j];
        else
          C[row * (size_t)N + col] = (OutT)f2b(acc[mf][nf][j]);
      }
}

// ---------------------------------------------------------------------------
// b/a projection + activation (fp32 in): beta = sigmoid(x@Wb^T),
// g = -exp(A_log) * softplus(x@Wa^T + dt_bias)   [log-decay, for chunk cumsum]
// ---------------------------------------------------------------------------
__global__ __launch_bounds__(256)
void k_proj_ba(const float* __restrict__ x, const float* __restrict__ Wb,
               const float* __restrict__ Wa, const float* __restrict__ dtb,
               const float* __restrict__ alog,
               float* __restrict__ beta, float* __restrict__ gout) {
  __shared__ float xs[HID_];
  __shared__ float part[32][8];
  const int bt = blockIdx.x, tid = threadIdx.x;
  const float* xr = x + (size_t)bt * HID_;
  *(float4*)&xs[tid * 8]     = *(const float4*)&xr[tid * 8];
  *(float4*)&xs[tid * 8 + 4] = *(const float4*)&xr[tid * 8 + 4];
  __syncthreads();
  const int o = tid >> 3, seg = tid & 7;
  const float* W = (o < 16) ? (Wb + (size_t)o * HID_) : (Wa + (size_t)(o - 16) * HID_);
  float s = 0.f;
  for (int k = seg * 256; k < seg * 256 + 256; k += 4) {
    float4 wv = *(const float4*)&W[k];
    float4 xv = *(const float4*)&xs[k];
    s += wv.x * xv.x + wv.y * xv.y + wv.z * xv.z + wv.w * xv.w;
  }
  part[o][seg] = s;
  __syncthreads();
  if (tid < 32) {
    float tsum = 0.f;
#pragma unroll
    for (int i = 0; i < 8; ++i) tsum += part[tid][i];
    if (tid < 16) {
      beta[(size_t)bt * NV_ + tid] = 1.f / (1.f + expf(-tsum));
    } else {
      const int h = tid - 16;
      float aa = tsum + dtb[h];
      float sp = (aa > 20.f) ? aa : log1pf(expf(aa));
      gout[(size_t)bt * NV_ + h] = -expf(alog[h]) * sp;
    }
  }
}

// ---------------------------------------------------------------------------
// Depthwise causal conv1d (K=4, left zero-pad) + silu, bf16 in -> fp32 out.
// ---------------------------------------------------------------------------
__global__ __launch_bounds__(256)
void k_conv_silu(const ushort_t* __restrict__ qkv, const float* __restrict__ cw,
                 float* __restrict__ act) {
  const unsigned idx = blockIdx.x * 256u + threadIdx.x;  // B*T*CD/4 total
  const unsigned c4  = idx & (CD_ / 4 - 1);
  const unsigned bt  = idx >> 10;                        // / (CD_/4)
  const int t = bt & (T_ - 1);
  const int c = c4 * 4;
  const ushort_t* rowp = qkv + (size_t)bt * CD_ + c;
  float wf[4][4];
#pragma unroll
  for (int i = 0; i < 4; ++i) {
    float4 w = *(const float4*)&cw[(c + i) * 4];
    wf[i][0] = w.x; wf[i][1] = w.y; wf[i][2] = w.z; wf[i][3] = w.w;
  }
  float a[4] = {0.f, 0.f, 0.f, 0.f};
#pragma unroll
  for (int j = 0; j < 4; ++j) {
    const int tt = t - 3 + j;
    if (tt >= 0) {
      short4v iv = *(const short4v*)(rowp + ((ptrdiff_t)j - 3) * CD_);
#pragma unroll
      for (int i = 0; i < 4; ++i) a[i] += b2f((ushort_t)iv[i]) * wf[i][j];
    }
  }
  float4 o;
  o.x = a[0] / (1.f + expf(-a[0]));
  o.y = a[1] / (1.f + expf(-a[1]));
  o.z = a[2] / (1.f + expf(-a[2]));
  o.w = a[3] / (1.f + expf(-a[3]));
  *(float4*)(act + (size_t)bt * CD_ + c) = o;
}

// ---------------------------------------------------------------------------
// L2-normalize q (with HD^-1/2 scale) and k rows in-place (fp32). Wave per row.
// ---------------------------------------------------------------------------
__global__ __launch_bounds__(256)
void k_l2norm_qk(float* __restrict__ act) {
  const int row  = blockIdx.x * 4 + (threadIdx.x >> 6);  // B*T*16 rows
  const int lane = threadIdx.x & 63;
  const int bt = row >> 4, s = row & 15;
  float* p = act + (size_t)bt * CD_ + (s < 8 ? s * HD_ : KD_ + (s - 8) * HD_);
  float2 v = *(float2*)&p[lane * 2];
  float ss = v.x * v.x + v.y * v.y;
#pragma unroll
  for (int m = 1; m < 64; m <<= 1) ss += __shfl_xor(ss, m);
  float scale = 1.f / fmaxf(sqrtf(ss), 1e-12f);
  if (s < 8) scale *= 0.08838834764831845f;  // HD^-0.5
  v.x *= scale; v.y *= scale;
  *(float2*)&p[lane * 2] = v;
}

// ---------------------------------------------------------------------------
__device__ __forceinline__ bf16x8 cvt8f(const float* p) {
  float4 a = *(const float4*)p;
  float4 b = *(const float4*)(p + 4);
  bf16x8 o;
  o[0] = (__bf16)a.x; o[1] = (__bf16)a.y; o[2] = (__bf16)a.z; o[3] = (__bf16)a.w;
  o[4] = (__bf16)b.x; o[5] = (__bf16)b.y; o[6] = (__bf16)b.z; o[7] = (__bf16)b.w;
  return o;
}

// ---------------------------------------------------------------------------
// k_prep: per-chunk parallel precompute. grid = B*NV*NC = 1024. (unchanged R6)
// ---------------------------------------------------------------------------
__global__ __launch_bounds__(256, 1)
void k_prep(const float* __restrict__ act, const float* __restrict__ gB,
            const float* __restrict__ betaB,
            ushort_t* __restrict__ WkG, ushort_t* __restrict__ UlG,
            ushort_t* __restrict__ PmG, ushort_t* __restrict__ kTG,
            float* __restrict__ gtG) {
  __shared__ __bf16 Kl[64][136];
  __shared__ __bf16 AbL[64][40];
  __shared__ __bf16 AbH[32][33];
  __shared__ __bf16 Xl[64][256];
  __shared__ float gc[65], Et[65], Rt[65], bts[64], geT[64];

  const int wg = blockIdx.x;                 // ((b*16+h)*32 + c)
  const int c = wg & 31, h = (wg >> 5) & 15, b = wg >> 9;
  const int hq = h >> 1, t0 = c * 64;
  const int tid = threadIdx.x, lane = tid & 63, wave = tid >> 6;
  const int l15 = lane & 15, kcol0 = (lane >> 4) * 8, rrow = (lane >> 4) * 4;
  const size_t bhc = (size_t)wg;

  const float* baseQ = act + (size_t)b * T_ * CD_ + hq * HD_;
  const float* baseK = baseQ + KD_;

  if (tid < 64) {
    float g = gB[((size_t)b * T_ + t0 + tid) * NV_ + h];
    bts[tid] = betaB[((size_t)b * T_ + t0 + tid) * NV_ + h];
#pragma unroll
    for (int o = 1; o < 64; o <<= 1) {
      float up = __shfl_up(g, (unsigned)o);
      if (tid >= o) g += up;
    }
    gc[tid + 1] = g;
    if (tid == 0) gc[0] = 0.f;
  }
  __syncthreads();
  if (tid < 65) {
    float gm = gc[32];
    Et[tid] = __expf(gc[tid] - gm);
    Rt[tid] = __expf(gm - gc[tid]);
  }
  if (tid < 64) {
    geT[tid] = bts[tid] * __expf(gc[tid + 1]);
    gtG[bhc * 64 + tid] = gc[tid + 1];
  }
  {
    const int t = tid >> 2, d0 = (tid & 3) * 32;
    const float* src = baseK + (size_t)(t0 + t) * CD_ + d0;
#pragma unroll
    for (int j = 0; j < 8; ++j) {
      float4 v = *(const float4*)(src + j * 4);
      Kl[t][d0 + j * 4 + 0] = (__bf16)v.x;
      Kl[t][d0 + j * 4 + 1] = (__bf16)v.y;
      Kl[t][d0 + j * 4 + 2] = (__bf16)v.z;
      Kl[t][d0 + j * 4 + 3] = (__bf16)v.w;
    }
  }
  __syncthreads();

  {
    bf16x8 kf[4], qf[4];
#pragma unroll
    for (int kk = 0; kk < 4; ++kk) {
      kf[kk] = *(const bf16x8*)&Kl[16 * wave + l15][kk * 32 + kcol0];
      qf[kk] = cvt8f(baseQ + (size_t)(t0 + 16 * wave + l15) * CD_ + kk * 32 + kcol0);
    }
#pragma unroll
    for (int st = 0; st < 4; ++st) {
      f32x4 accA = {}, accP = {};
#pragma unroll
      for (int kk = 0; kk < 4; ++kk) {
        bf16x8 bfr = *(const bf16x8*)&Kl[st * 16 + l15][kk * 32 + kcol0];
        accA = __builtin_amdgcn_mfma_f32_16x16x32_bf16(kf[kk], bfr, accA, 0, 0, 0);
        accP = __builtin_amdgcn_mfma_f32_16x16x32_bf16(qf[kk], bfr, accP, 0, 0, 0);
      }
      const int scol = st * 16 + l15;
#pragma unroll
      for (int r = 0; r < 4; ++r) {
        const int t = 16 * wave + rrow + r;
        const float sc = Et[t + 1] * Rt[scol + 1];
        if (scol < t) {
          const float av = -bts[t] * sc * accA[r];
          if (scol < 32) AbL[t][scol] = (__bf16)av;
          else           AbH[t - 32][scol - 32] = (__bf16)av;
        }
        PmG[bhc * 4608 + (size_t)t * 72 + scol] =
            (scol <= t) ? f2b(sc * accP[r]) : (ushort_t)0;
      }
    }
  }
  if ((h & 1) == 0) {
    const size_t kto = (((size_t)b * 8 + hq) * 32 + c) * (128 * 72);
    const int d = tid >> 1, t8 = (tid & 1) * 32;
#pragma unroll
    for (int i8 = 0; i8 < 4; ++i8) {
      bf16x8 tmp;
#pragma unroll
      for (int jj = 0; jj < 8; ++jj) tmp[jj] = Kl[t8 + i8 * 8 + jj][d];
      *(bf16x8*)(void*)(kTG + kto + (size_t)d * 72 + t8 + i8 * 8) = tmp;
    }
  }
  __syncthreads();

  {
    float r1[32], r2[32];
    if (tid < 128) {
      const int d = tid;
#pragma unroll
      for (int t = 0; t < 32; ++t) r1[t] = geT[t] * (float)Kl[t][d];
#pragma unroll
      for (int t = 0; t < 32; ++t) r2[t] = geT[32 + t] * (float)Kl[32 + t][d];
    } else {
      const int j = tid - 128;
      const float* vsrc = act + ((size_t)b * T_ + t0) * CD_ + 2 * KD_ + h * HD_ + j;
#pragma unroll
      for (int t = 0; t < 32; ++t) r1[t] = bts[t] * vsrc[(size_t)t * CD_];
#pragma unroll
      for (int t = 0; t < 32; ++t) r2[t] = bts[32 + t] * vsrc[(size_t)(32 + t) * CD_];
    }
    float u1[32];
#pragma unroll
    for (int j = 0; j < 32; ++j) {
      float a = r1[j];
#pragma unroll
      for (int i = 0; i < j; ++i) a += (float)AbL[j][i] * u1[i];
      u1[j] = a;
      Xl[j][tid] = (__bf16)a;
    }
#pragma unroll
    for (int t2 = 0; t2 < 32; ++t2) {
      float a = r2[t2];
#pragma unroll
      for (int i = 0; i < 32; ++i) a += (float)AbL[32 + t2][i] * u1[i];
      r2[t2] = a;
    }
    float u2[32];
#pragma unroll
    for (int j = 0; j < 32; ++j) {
      float a = r2[j];
#pragma unroll
      for (int i = 0; i < j; ++i) a += (float)AbH[j][i] * u2[i];
      u2[j] = a;
      Xl[32 + j][tid] = (__bf16)a;
    }
  }
  __syncthreads();

#pragma unroll
  for (int kck = 0; kck < 4; ++kck) {
    const int q = tid + kck * 256;             // 0..1023
    const int t = q >> 4, d0 = (q & 15) * 8;
    uint4 v = *(const uint4*)&Xl[t][d0];
    v.x ^= 0x80008000u; v.y ^= 0x80008000u; v.z ^= 0x80008000u; v.w ^= 0x80008000u;
    *(uint4*)(void*)(WkG + bhc * (64 * 136) + (size_t)t * 136 + d0) = v;
    uint4 w = *(const uint4*)&Xl[t][128 + d0];
    *(uint4*)(void*)(UlG + bhc * (64 * 136) + (size_t)t * 136 + d0) = w;
  }
}

// ---------------------------------------------------------------------------
// k_scan: sequential inter-chunk state recurrence + fused output. grid = B*NV.
// (R6 version — known 192 us; R7 register-prefetch variant regressed.)
// ---------------------------------------------------------------------------
__global__ __launch_bounds__(256, 1)
void k_scan(const float* __restrict__ act,
            const ushort_t* __restrict__ WkG, const ushort_t* __restrict__ UlG,
            const ushort_t* __restrict__ PmG, const ushort_t* __restrict__ kTG,
            const float* __restrict__ gtG, float* __restrict__ ob) {
  __shared__ __bf16 S16[128][136];   // 34816 B
  __shared__ __bf16 uTl[128][72];    // 18432 B
  __shared__ float gam[64], esc[64];

  const int wg = blockIdx.x;                 // b*16 + h
  const int h = wg & 15, b = wg >> 4, hq = h >> 1;
  const int tid = threadIdx.x, lane = tid & 63, wave = tid >> 6;
  const int l15 = lane & 15, kcol0 = (lane >> 4) * 8, rrow = (lane >> 4) * 4;

  f32x4 s_acc[2][8] = {};    // j-tiles {2w,2w+1} x 8 d-tiles

  for (int c = 0; c < 32; ++c) {
    const size_t bhc = (size_t)wg * 32 + c;
    const int t0g = c * 64;
    const ushort_t* WkR = WkG + bhc * (64 * 136);
    const ushort_t* UlR = UlG + bhc * (64 * 136);
    const ushort_t* PmR = PmG + bhc * 4608;
    const ushort_t* kTR = kTG + (((size_t)b * 8 + hq) * 32 + c) * (128 * 72);

    const float gCv = gtG[bhc * 64 + 63];
    if (tid < 64) {
      const float gv = gtG[bhc * 64 + tid];
      gam[tid] = __expf(gv);
      esc[tid] = __expf(gCv - gv);
    }
    // S16 <- bf16(S)
#pragma unroll
    for (int jt2 = 0; jt2 < 2; ++jt2)
#pragma unroll
      for (int dt = 0; dt < 8; ++dt)
#pragma unroll
        for (int r = 0; r < 4; ++r)
          S16[(2 * wave + jt2) * 16 + rrow + r][dt * 16 + l15] = (__bf16)s_acc[jt2][dt][r];
    __syncthreads();

    // u-phase: u = Uloc + (-Wk)@S
    bf16x8 wa[4];
#pragma unroll
    for (int kk = 0; kk < 4; ++kk)
      wa[kk] = *(const bf16x8*)(const void*)(WkR + (size_t)(16 * wave + l15) * 136 + kk * 32 + kcol0);
    float uv[8][4];
#pragma unroll
    for (int jt = 0; jt < 8; ++jt)
#pragma unroll
      for (int r = 0; r < 4; ++r)
        uv[jt][r] = b2f(UlR[(size_t)(16 * wave + rrow + r) * 136 + jt * 16 + l15]);
    f32x4 au[8] = {};
#pragma unroll
    for (int kk = 0; kk < 4; ++kk)
#pragma unroll
      for (int jt = 0; jt < 8; ++jt) {
        bf16x8 sb = *(const bf16x8*)&S16[jt * 16 + l15][kk * 32 + kcol0];
        au[jt] = __builtin_amdgcn_mfma_f32_16x16x32_bf16(wa[kk], sb, au[jt], 0, 0, 0);
      }
#pragma unroll
    for (int jt = 0; jt < 8; ++jt)
#pragma unroll
      for (int r = 0; r < 4; ++r)
        uTl[jt * 16 + l15][16 * wave + rrow + r] = (__bf16)(au[jt][r] + uv[jt][r]);
    __syncthreads();

    // QS + o2 = Pm@u; o = gam*QS + o2 -> obuf
    f32x4 qs[8] = {}, o2[8] = {};
#pragma unroll
    for (int kk = 0; kk < 4; ++kk) {
      bf16x8 qa = cvt8f(act + ((size_t)b * T_ + t0g + 16 * wave + l15) * CD_ + hq * HD_ + kk * 32 + kcol0);
#pragma unroll
      for (int jt = 0; jt < 8; ++jt) {
        bf16x8 sb = *(const bf16x8*)&S16[jt * 16 + l15][kk * 32 + kcol0];
        qs[jt] = __builtin_amdgcn_mfma_f32_16x16x32_bf16(qa, sb, qs[jt], 0, 0, 0);
      }
    }
#pragma unroll
    for (int ks = 0; ks < 2; ++ks) {
      bf16x8 pa = *(const bf16x8*)(const void*)(PmR + (size_t)(16 * wave + l15) * 72 + ks * 32 + kcol0);
#pragma unroll
      for (int jt = 0; jt < 8; ++jt) {
        bf16x8 ub = *(const bf16x8*)&uTl[jt * 16 + l15][ks * 32 + kcol0];
        o2[jt] = __builtin_amdgcn_mfma_f32_16x16x32_bf16(pa, ub, o2[jt], 0, 0, 0);
      }
    }
#pragma unroll
    for (int jt = 0; jt < 8; ++jt)
#pragma unroll
      for (int r = 0; r < 4; ++r) {
        const int t = 16 * wave + rrow + r;
        ob[(((size_t)b * T_ + t0g + t) * NV_ + h) * HD_ + jt * 16 + l15] =
            gam[t] * qs[jt][r] + o2[jt][r];
      }

    // S-update: S = gam[63]*S + K^T (esc*u)
    const float gCe = gam[63];
#pragma unroll
    for (int jt2 = 0; jt2 < 2; ++jt2)
#pragma unroll
      for (int dt = 0; dt < 8; ++dt)
#pragma unroll
        for (int r = 0; r < 4; ++r) s_acc[jt2][dt][r] *= gCe;
#pragma unroll
    for (int ks = 0; ks < 2; ++ks) {
      bf16x8 ua[2];
#pragma unroll
      for (int jt2 = 0; jt2 < 2; ++jt2) {
        bf16x8 raw = *(const bf16x8*)&uTl[(2 * wave + jt2) * 16 + l15][ks * 32 + kcol0];
#pragma unroll
        for (int e = 0; e < 8; ++e)
          ua[jt2][e] = (__bf16)((float)raw[e] * esc[ks * 32 + kcol0 + e]);
      }
#pragma unroll
      for (int dt = 0; dt < 8; ++dt) {
        bf16x8 kb = *(const bf16x8*)(const void*)(kTR + (size_t)(dt * 16 + l15) * 72 + ks * 32 + kcol0);
        s_acc[0][dt] = __builtin_amdgcn_mfma_f32_16x16x32_bf16(ua[0], kb, s_acc[0][dt], 0, 0, 0);
        s_acc[1][dt] = __builtin_amdgcn_mfma_f32_16x16x32_bf16(ua[1], kb, s_acc[1][dt], 0, 0, 0);
      }
    }
    __syncthreads();
  }
}

// ---------------------------------------------------------------------------
// Gated RMSNorm: out = (o/rms(o)) * norm_w * silu(z); fp32 o, bf16 z,
// fp32 norm_w -> bf16 out (final GEMM operand).
// ---------------------------------------------------------------------------
__global__ __launch_bounds__(256)
void k_gate_rms(const float* __restrict__ ob, const ushort_t* __restrict__ z,
                const float* __restrict__ nw, ushort_t* __restrict__ og) {
  const int row  = blockIdx.x * 4 + (threadIdx.x >> 6);  // B*T*NV rows
  const int lane = threadIdx.x & 63;
  const float* op = ob + (size_t)row * HD_;
  float2 v = *(const float2*)&op[lane * 2];
  float ss = v.x * v.x + v.y * v.y;
#pragma unroll
  for (int m = 1; m < 64; m <<= 1) ss += __shfl_xor(ss, m);
  const float r = 1.f / sqrtf(ss * (1.f / HD_) + 1e-6f);
  unsigned int zz = *(const unsigned int*)&z[(size_t)row * HD_ + lane * 2];
  float z0 = b2f((ushort_t)(zz & 0xffffu));
  float z1 = b2f((ushort_t)(zz >> 16));
  float2 w = *(const float2*)&nw[lane * 2];
  float g0 = z0 / (1.f + expf(-z0));
  float g1 = z1 / (1.f + expf(-z1));
  unsigned int pack = (unsigned int)f2b(v.x * r * w.x * g0)
                    | ((unsigned int)f2b(v.y * r * w.y * g1) << 16);
  *(unsigned int*)&og[(size_t)row * HD_ + lane * 2] = pack;
}

// ---------------------------------------------------------------------------
extern "C" void kernel_launch(void* const* d_in, const int* in_sizes, int n_in,
                              void* d_out, int out_size, void* d_ws, size_t ws_size,
                              hipStream_t stream) {
  const float* x    = (const float*)d_in[0];
  const float* Wqkv = (const float*)d_in[1];
  const float* Wz   = (const float*)d_in[2];
  const float* Wb   = (const float*)d_in[3];
  const float* Wa   = (const float*)d_in[4];
  const float* cw   = (const float*)d_in[5];
  const float* dtb  = (const float*)d_in[6];
  const float* alog = (const float*)d_in[7];
  const float* nw   = (const float*)d_in[8];
  const float* Wout = (const float*)d_in[9];

  char* p = (char*)d_ws;
  ushort_t* qkv_raw = (ushort_t*)p; p += (size_t)B_ * T_ * CD_ * 2;       // 33.5 MB
  ushort_t* zbuf    = (ushort_t*)p; p += (size_t)B_ * T_ * VD_ * 2;       // 16.8 MB
  char*     actBase = p;
  float*    act     = (float*)p;    p += (size_t)B_ * T_ * CD_ * 4;       // 67.1 MB
  float*    betaB   = (float*)p;    p += (size_t)B_ * T_ * NV_ * 4;
  float*    gBuf    = (float*)p;    p += (size_t)B_ * T_ * NV_ * 4;
  float*    obuf    = (float*)p;    p += (size_t)B_ * T_ * NV_ * HD_ * 4; // 33.5 MB
  ushort_t* WoutB   = (ushort_t*)p; p += (size_t)HID_ * VD_ * 2;          // 8.4 MB
  ushort_t* UlG     = (ushort_t*)p; p += (size_t)1024 * 64 * 136 * 2;     // 17.8 MB
  ushort_t* PmG     = (ushort_t*)p; p += (size_t)1024 * 64 * 72 * 2;      //  9.4 MB
  // overlays in qkv_raw region (dead after conv; outg written after k_scan):
  ushort_t* WkG = qkv_raw;                                                // 17.8 MB
  ushort_t* kTG = (ushort_t*)((char*)qkv_raw + 17825792);                 //  9.4 MB
  float*    gtG = (float*)((char*)qkv_raw + 27262976);                    //  0.26 MB
  // bf16 cast buffers aliased into act region (dead before conv writes act):
  ushort_t* xB    = (ushort_t*)(actBase);                                 // 16.8 MB
  ushort_t* WqkvB = (ushort_t*)(actBase + (size_t)B_ * T_ * HID_ * 2);    // 16.8 MB
  ushort_t* WzB   = (ushort_t*)(actBase + (size_t)B_ * T_ * HID_ * 2
                                        + (size_t)CD_ * HID_ * 2);        // 8.4 MB
  ushort_t* outg  = qkv_raw;        // reuse again after k_scan

  const int M = B_ * T_;  // 4096

  hipLaunchKernelGGL(k_cast_bf16, dim3(M * HID_ / 4 / 256), dim3(256), 0, stream,
                     x, xB, M * HID_ / 4);
  hipLaunchKernelGGL(k_cast_bf16, dim3(CD_ * HID_ / 4 / 256), dim3(256), 0, stream,
                     Wqkv, WqkvB, CD_ * HID_ / 4);
  hipLaunchKernelGGL(k_cast_bf16, dim3(VD_ * HID_ / 4 / 256), dim3(256), 0, stream,
                     Wz, WzB, VD_ * HID_ / 4);
  hipLaunchKernelGGL(k_cast_bf16, dim3(HID_ * VD_ / 4 / 256), dim3(256), 0, stream,
                     Wout, WoutB, HID_ * VD_ / 4);

  hipLaunchKernelGGL(k_gemm256<ushort_t>, dim3((M / 256) * (CD_ / 256)), dim3(512), 0, stream,
                     xB, WqkvB, qkv_raw, M, CD_, HID_);
  hipLaunchKernelGGL(k_gemm256<ushort_t>, dim3((M / 256) * (VD_ / 256)), dim3(512), 0, stream,
                     xB, WzB, zbuf, M, VD_, HID_);
  hipLaunchKernelGGL(k_proj_ba, dim3(M), dim3(256), 0, stream,
                     x, Wb, Wa, dtb, alog, betaB, gBuf);
  hipLaunchKernelGGL(k_conv_silu, dim3(M * CD_ / 4 / 256), dim3(256), 0, stream,
                     qkv_raw, cw, act);
  hipLaunchKernelGGL(k_l2norm_qk, dim3(M * 16 / 4), dim3(256), 0, stream, act);
  hipLaunchKernelGGL(k_prep, dim3(B_ * NV_ * 32), dim3(256), 0, stream,
                     act, gBuf, betaB, WkG, UlG, PmG, kTG, gtG);
  hipLaunchKernelGGL(k_scan, dim3(B_ * NV_), dim3(256), 0, stream,
                     act, WkG, UlG, PmG, kTG, gtG, obuf);
  hipLaunchKernelGGL(k_gate_rms, dim3(M * NV_ / 4), dim3(256), 0, stream,
                     obuf, zbuf, nw, outg);
  hipLaunchKernelGGL(k_gemm256<float>, dim3((M / 256) * (HID_ / 256)), dim3(512), 0, stream,
                     outg, WoutB, (float*)d_out, M, HID_, VD_);
}

// Round 9
// 549.967 us; speedup vs baseline: 1.2999x; 1.1595x over previous
//
#include <hip/hip_runtime.h>
#include <cstdint>
#include <cstddef>

// GatedDeltaNet forward, MI355X/gfx950.
// Inputs/outputs are fp32 (reference computes in jnp.float32).
// Pipeline: cast(x,Wqkv,Wz,Wout->bf16) -> [gemm256 qkv] [proj b/a] -> conv1d+silu
//           -> l2norm q,k -> k_prep (parallel per chunk)
//           -> FUSED { k_scan (64 WGs, e-sliced, 8-wave) || z-gemm (128 WGs) }
//           -> gated RMSNorm*silu(z) -> [gemm256 out -> fp32 d_out].
// R9: (a) k_scan e-sliced: grid 32->64, 512 thr, per-wave MFMA 112->28, scalar
//     LDS/global ops cut ~4x; Uloc stored transposed (UlT[e][t]) by k_prep so
//     its add is two 8B loads. (b) z-gemm fused as extra blocks of the scan
//     launch (192 blocks co-resident) - hides ~50us under the scan.

typedef unsigned short ushort_t;
typedef __attribute__((ext_vector_type(8))) __bf16 bf16x8;
typedef __attribute__((ext_vector_type(4))) float f32x4;
typedef __attribute__((ext_vector_type(4))) short short4v;

#define B_   2
#define T_   2048
#define HID_ 2048
#define NK_  8
#define NV_  16
#define HD_  128
#define KD_  1024
#define VD_  2048
#define CD_  4096

__device__ __forceinline__ float b2f(ushort_t u) {
  union { unsigned int i; float f; } v; v.i = ((unsigned int)u) << 16; return v.f;
}
__device__ __forceinline__ ushort_t f2b(float f) {   // RNE bf16 round
  unsigned int x = __builtin_bit_cast(unsigned int, f);
  unsigned int r = x + 0x7fffu + ((x >> 16) & 1u);
  return (ushort_t)(r >> 16);
}

// ---------------------------------------------------------------------------
// fp32 -> bf16 cast
// ---------------------------------------------------------------------------
__global__ __launch_bounds__(256)
void k_cast_bf16(const float* __restrict__ in, ushort_t* __restrict__ out, int n4) {
  const int i = blockIdx.x * 256 + threadIdx.x;
  if (i >= n4) return;
  float4 v = *(const float4*)(in + (size_t)i * 4);
  short4v o;
  o[0] = (short)f2b(v.x); o[1] = (short)f2b(v.y);
  o[2] = (short)f2b(v.z); o[3] = (short)f2b(v.w);
  *(short4v*)(out + (size_t)i * 4) = o;
}

// ---------------------------------------------------------------------------
// GEMM 256x256 body, BK=64, 8 waves, counted-vmcnt pipeline (R8-verified).
// lds: 2x2x2x8192 ushort = 128 KB, passed as raw pointer.
// ---------------------------------------------------------------------------
#define LPOS(BUF, OP, HALF) ((((BUF) * 2 + (OP)) * 2 + (HALF)) * 8192)

template <typename OutT>
__device__ __forceinline__ void gemm256_body(
    const ushort_t* __restrict__ A, const ushort_t* __restrict__ Bw,
    OutT* __restrict__ C, int M, int N, int K, int tile, ushort_t* lds) {
  const int tid = threadIdx.x;
  const int lane = tid & 63, wave = tid >> 6;
  const int wm = wave >> 2, wc = wave & 3;
  const int l15 = lane & 15;
  const int ks16 = (lane >> 4) * 16;
  const int r4 = (lane >> 4) * 4;
  const int nkt = K >> 6;
  const int nbx = N >> 8;
  const size_t row0 = (size_t)(tile / nbx) * 256;
  const size_t col0 = (size_t)(tile % nbx) * 256;

#define STAGE4(BUF, HALF, KT) {                                               \
    const int kt_ = ((KT) < nkt) ? (KT) : (nkt - 1);                          \
    const int kb_ = kt_ * 64 + (HALF) * 32;                                   \
    _Pragma("unroll") for (int r_ = 0; r_ < 2; ++r_) {                        \
      const int wb_ = r_ * 8192 + wave * 1024;                                \
      const int o_  = wb_ + lane * 16;                                        \
      const int row_ = o_ >> 6;                                               \
      const int src_ = (o_ & 63) ^ (((row_) & 3) << 4);                       \
      const ushort_t* ga_ = A  + (row0 + row_) * (size_t)K + kb_ + (src_ >> 1); \
      const ushort_t* gb_ = Bw + (col0 + row_) * (size_t)K + kb_ + (src_ >> 1); \
      __builtin_amdgcn_global_load_lds(                                       \
          (const __attribute__((address_space(1))) unsigned int*)ga_,         \
          (__attribute__((address_space(3))) unsigned int*)                   \
              (lds + LPOS(BUF, 0, HALF) + (wb_ >> 1)), 16, 0, 0);             \
      __builtin_amdgcn_global_load_lds(                                       \
          (const __attribute__((address_space(1))) unsigned int*)gb_,         \
          (__attribute__((address_space(3))) unsigned int*)                   \
              (lds + LPOS(BUF, 1, HALF) + (wb_ >> 1)), 16, 0, 0);             \
    }                                                                         \
  }

#define RD(BUF, OP, HALF, ROW)                                                \
  (*(const bf16x8*)((const char*)(lds + LPOS(BUF, OP, HALF)) +                \
                    ((((ROW) * 64 + ks16)) ^ (((ROW) & 3) << 4))))

  f32x4 acc[8][4] = {};
  STAGE4(0, 0, 0)
  STAGE4(0, 1, 0)
  STAGE4(1, 0, 1)

  for (int kt = 0; kt < nkt; ++kt) {
    const int cb = kt & 1, nb = cb ^ 1;
    asm volatile("s_waitcnt vmcnt(8)" ::: "memory");
    __builtin_amdgcn_s_barrier();
    {
      bf16x8 af[8], bfr[4];
#pragma unroll
      for (int mf = 0; mf < 8; ++mf) af[mf] = RD(cb, 0, 0, wm * 128 + mf * 16 + l15);
#pragma unroll
      for (int nf = 0; nf < 4; ++nf) bfr[nf] = RD(cb, 1, 0, wc * 64 + nf * 16 + l15);
      STAGE4(nb, 1, kt + 1)
      __builtin_amdgcn_s_setprio(1);
#pragma unroll
      for (int mf = 0; mf < 8; ++mf)
#pragma unroll
        for (int nf = 0; nf < 4; ++nf)
          acc[mf][nf] = __builtin_amdgcn_mfma_f32_16x16x32_bf16(af[mf], bfr[nf], acc[mf][nf], 0, 0, 0);
      __builtin_amdgcn_s_setprio(0);
    }
    asm volatile("s_waitcnt vmcnt(8)" ::: "memory");
    __builtin_amdgcn_s_barrier();
    {
      bf16x8 af[8], bfr[4];
#pragma unroll
      for (int mf = 0; mf < 8; ++mf) af[mf] = RD(cb, 0, 1, wm * 128 + mf * 16 + l15);
#pragma unroll
      for (int nf = 0; nf < 4; ++nf) bfr[nf] = RD(cb, 1, 1, wc * 64 + nf * 16 + l15);
      STAGE4(cb, 0, kt + 2)
      __builtin_amdgcn_s_setprio(1);
#pragma unroll
      for (int mf = 0; mf < 8; ++mf)
#pragma unroll
        for (int nf = 0; nf < 4; ++nf)
          acc[mf][nf] = __builtin_amdgcn_mfma_f32_16x16x32_bf16(af[mf], bfr[nf], acc[mf][nf], 0, 0, 0);
      __builtin_amdgcn_s_setprio(0);
    }
  }
#undef STAGE4
#undef RD

#pragma unroll
  for (int mf = 0; mf < 8; ++mf)
#pragma unroll
    for (int nf = 0; nf < 4; ++nf)
#pragma unroll
      for (int j = 0; j < 4; ++j) {
        const size_t row = row0 + wm * 128 + mf * 16 + r4 + j;
        const size_t col = col0 + wc * 64 + nf * 16 + l15;
        if constexpr (sizeof(OutT) == 4)
          C[row * (size_t)N + col] = acc[mf][nf][j];
        else
          C[row * (size_t)N + col] = (OutT)f2b(acc[mf][nf][j]);
      }
}

// standalone GEMM kernel (XCD-swizzled) for qkv / out projections
template <typename OutT>
__global__ __launch_bounds__(512, 2)
void k_gemm256(const ushort_t* __restrict__ A, const ushort_t* __restrict__ Bw,
               OutT* __restrict__ C, int M, int N, int K) {
  __shared__ alignas(16) ushort_t lds[2 * 2 * 2 * 8192];
  const int nwg = gridDim.x;
  const int q8 = nwg >> 3, r8 = nwg & 7;
  const int xcd = blockIdx.x & 7, idx8 = blockIdx.x >> 3;
  const int s = (xcd < r8) ? (xcd * (q8 + 1) + idx8)
                           : (r8 * (q8 + 1) + (xcd - r8) * q8 + idx8);
  gemm256_body<OutT>(A, Bw, C, M, N, K, s, lds);
}

// ---------------------------------------------------------------------------
// b/a projection: beta = sigmoid(x@Wb^T), g = -exp(A_log)*softplus(x@Wa^T+dtb)
// ---------------------------------------------------------------------------
__global__ __launch_bounds__(256)
void k_proj_ba(const float* __restrict__ x, const float* __restrict__ Wb,
               const float* __restrict__ Wa, const float* __restrict__ dtb,
               const float* __restrict__ alog,
               float* __restrict__ beta, float* __restrict__ gout) {
  __shared__ float xs[HID_];
  __shared__ float part[32][8];
  const int bt = blockIdx.x, tid = threadIdx.x;
  const float* xr = x + (size_t)bt * HID_;
  *(float4*)&xs[tid * 8]     = *(const float4*)&xr[tid * 8];
  *(float4*)&xs[tid * 8 + 4] = *(const float4*)&xr[tid * 8 + 4];
  __syncthreads();
  const int o = tid >> 3, seg = tid & 7;
  const float* W = (o < 16) ? (Wb + (size_t)o * HID_) : (Wa + (size_t)(o - 16) * HID_);
  float s = 0.f;
  for (int k = seg * 256; k < seg * 256 + 256; k += 4) {
    float4 wv = *(const float4*)&W[k];
    float4 xv = *(const float4*)&xs[k];
    s += wv.x * xv.x + wv.y * xv.y + wv.z * xv.z + wv.w * xv.w;
  }
  part[o][seg] = s;
  __syncthreads();
  if (tid < 32) {
    float tsum = 0.f;
#pragma unroll
    for (int i = 0; i < 8; ++i) tsum += part[tid][i];
    if (tid < 16) {
      beta[(size_t)bt * NV_ + tid] = 1.f / (1.f + expf(-tsum));
    } else {
      const int h = tid - 16;
      float aa = tsum + dtb[h];
      float sp = (aa > 20.f) ? aa : log1pf(expf(aa));
      gout[(size_t)bt * NV_ + h] = -expf(alog[h]) * sp;
    }
  }
}

// ---------------------------------------------------------------------------
// Depthwise causal conv1d (K=4) + silu, bf16 in -> fp32 out.
// ---------------------------------------------------------------------------
__global__ __launch_bounds__(256)
void k_conv_silu(const ushort_t* __restrict__ qkv, const float* __restrict__ cw,
                 float* __restrict__ act) {
  const unsigned idx = blockIdx.x * 256u + threadIdx.x;
  const unsigned c4  = idx & (CD_ / 4 - 1);
  const unsigned bt  = idx >> 10;
  const int t = bt & (T_ - 1);
  const int c = c4 * 4;
  const ushort_t* rowp = qkv + (size_t)bt * CD_ + c;
  float wf[4][4];
#pragma unroll
  for (int i = 0; i < 4; ++i) {
    float4 w = *(const float4*)&cw[(c + i) * 4];
    wf[i][0] = w.x; wf[i][1] = w.y; wf[i][2] = w.z; wf[i][3] = w.w;
  }
  float a[4] = {0.f, 0.f, 0.f, 0.f};
#pragma unroll
  for (int j = 0; j < 4; ++j) {
    const int tt = t - 3 + j;
    if (tt >= 0) {
      short4v iv = *(const short4v*)(rowp + ((ptrdiff_t)j - 3) * CD_);
#pragma unroll
      for (int i = 0; i < 4; ++i) a[i] += b2f((ushort_t)iv[i]) * wf[i][j];
    }
  }
  float4 o;
  o.x = a[0] / (1.f + expf(-a[0]));
  o.y = a[1] / (1.f + expf(-a[1]));
  o.z = a[2] / (1.f + expf(-a[2]));
  o.w = a[3] / (1.f + expf(-a[3]));
  *(float4*)(act + (size_t)bt * CD_ + c) = o;
}

// ---------------------------------------------------------------------------
// L2-normalize q (HD^-1/2 scale) and k rows in-place.
// ---------------------------------------------------------------------------
__global__ __launch_bounds__(256)
void k_l2norm_qk(float* __restrict__ act) {
  const int row  = blockIdx.x * 4 + (threadIdx.x >> 6);
  const int lane = threadIdx.x & 63;
  const int bt = row >> 4, s = row & 15;
  float* p = act + (size_t)bt * CD_ + (s < 8 ? s * HD_ : KD_ + (s - 8) * HD_);
  float2 v = *(float2*)&p[lane * 2];
  float ss = v.x * v.x + v.y * v.y;
#pragma unroll
  for (int m = 1; m < 64; m <<= 1) ss += __shfl_xor(ss, m);
  float scale = 1.f / fmaxf(sqrtf(ss), 1e-12f);
  if (s < 8) scale *= 0.08838834764831845f;
  v.x *= scale; v.y *= scale;
  *(float2*)&p[lane * 2] = v;
}

// ---------------------------------------------------------------------------
__device__ __forceinline__ bf16x8 cvt8f(const float* p) {
  float4 a = *(const float4*)p;
  float4 b = *(const float4*)(p + 4);
  bf16x8 o;
  o[0] = (__bf16)a.x; o[1] = (__bf16)a.y; o[2] = (__bf16)a.z; o[3] = (__bf16)a.w;
  o[4] = (__bf16)b.x; o[5] = (__bf16)b.y; o[6] = (__bf16)b.z; o[7] = (__bf16)b.w;
  return o;
}

// ---------------------------------------------------------------------------
// k_prep: per-chunk parallel precompute. grid = 1024.
// Outputs: WkG[bhc][64 t][136 d] (negated), UlT[bhc][128 e][72 t] (TRANSPOSED),
//          PmG[bhc][64][72], kTG[b][hq][c][128 d][72 t], gtG[bhc][64].
// ---------------------------------------------------------------------------
__global__ __launch_bounds__(256, 1)
void k_prep(const float* __restrict__ act, const float* __restrict__ gB,
            const float* __restrict__ betaB,
            ushort_t* __restrict__ WkG, ushort_t* __restrict__ UlT,
            ushort_t* __restrict__ PmG, ushort_t* __restrict__ kTG,
            float* __restrict__ gtG) {
  __shared__ __bf16 Kl[64][136];
  __shared__ __bf16 AbL[64][40];
  __shared__ __bf16 AbH[32][33];
  __shared__ __bf16 Xl[64][264];          // 264: 16B-aligned rows, decent banks
  __shared__ float gc[65], Et[65], Rt[65], bts[64], geT[64];

  const int wg = blockIdx.x;
  const int c = wg & 31, h = (wg >> 5) & 15, b = wg >> 9;
  const int hq = h >> 1, t0 = c * 64;
  const int tid = threadIdx.x, lane = tid & 63, wave = tid >> 6;
  const int l15 = lane & 15, kcol0 = (lane >> 4) * 8, rrow = (lane >> 4) * 4;
  const size_t bhc = (size_t)wg;

  const float* baseQ = act + (size_t)b * T_ * CD_ + hq * HD_;
  const float* baseK = baseQ + KD_;

  if (tid < 64) {
    float g = gB[((size_t)b * T_ + t0 + tid) * NV_ + h];
    bts[tid] = betaB[((size_t)b * T_ + t0 + tid) * NV_ + h];
#pragma unroll
    for (int o = 1; o < 64; o <<= 1) {
      float up = __shfl_up(g, (unsigned)o);
      if (tid >= o) g += up;
    }
    gc[tid + 1] = g;
    if (tid == 0) gc[0] = 0.f;
  }
  __syncthreads();
  if (tid < 65) {
    float gm = gc[32];
    Et[tid] = __expf(gc[tid] - gm);
    Rt[tid] = __expf(gm - gc[tid]);
  }
  if (tid < 64) {
    geT[tid] = bts[tid] * __expf(gc[tid + 1]);
    gtG[bhc * 64 + tid] = gc[tid + 1];
  }
  {
    const int t = tid >> 2, d0 = (tid & 3) * 32;
    const float* src = baseK + (size_t)(t0 + t) * CD_ + d0;
#pragma unroll
    for (int j = 0; j < 8; ++j) {
      float4 v = *(const float4*)(src + j * 4);
      Kl[t][d0 + j * 4 + 0] = (__bf16)v.x;
      Kl[t][d0 + j * 4 + 1] = (__bf16)v.y;
      Kl[t][d0 + j * 4 + 2] = (__bf16)v.z;
      Kl[t][d0 + j * 4 + 3] = (__bf16)v.w;
    }
  }
  __syncthreads();

  {
    bf16x8 kf[4], qf[4];
#pragma unroll
    for (int kk = 0; kk < 4; ++kk) {
      kf[kk] = *(const bf16x8*)&Kl[16 * wave + l15][kk * 32 + kcol0];
      qf[kk] = cvt8f(baseQ + (size_t)(t0 + 16 * wave + l15) * CD_ + kk * 32 + kcol0);
    }
#pragma unroll
    for (int st = 0; st < 4; ++st) {
      f32x4 accA = {}, accP = {};
#pragma unroll
      for (int kk = 0; kk < 4; ++kk) {
        bf16x8 bfr = *(const bf16x8*)&Kl[st * 16 + l15][kk * 32 + kcol0];
        accA = __builtin_amdgcn_mfma_f32_16x16x32_bf16(kf[kk], bfr, accA, 0, 0, 0);
        accP = __builtin_amdgcn_mfma_f32_16x16x32_bf16(qf[kk], bfr, accP, 0, 0, 0);
      }
      const int scol = st * 16 + l15;
#pragma unroll
      for (int r = 0; r < 4; ++r) {
        const int t = 16 * wave + rrow + r;
        const float sc = Et[t + 1] * Rt[scol + 1];
        if (scol < t) {
          const float av = -bts[t] * sc * accA[r];
          if (scol < 32) AbL[t][scol] = (__bf16)av;
          else           AbH[t - 32][scol - 32] = (__bf16)av;
        }
        PmG[bhc * 4608 + (size_t)t * 72 + scol] =
            (scol <= t) ? f2b(sc * accP[r]) : (ushort_t)0;
      }
    }
  }
  if ((h & 1) == 0) {
    const size_t kto = (((size_t)b * 8 + hq) * 32 + c) * (128 * 72);
    const int d = tid >> 1, t8 = (tid & 1) * 32;
#pragma unroll
    for (int i8 = 0; i8 < 4; ++i8) {
      bf16x8 tmp;
#pragma unroll
      for (int jj = 0; jj < 8; ++jj) tmp[jj] = Kl[t8 + i8 * 8 + jj][d];
      *(bf16x8*)(void*)(kTG + kto + (size_t)d * 72 + t8 + i8 * 8) = tmp;
    }
  }
  __syncthreads();

  {
    float r1[32], r2[32];
    if (tid < 128) {
      const int d = tid;
#pragma unroll
      for (int t = 0; t < 32; ++t) r1[t] = geT[t] * (float)Kl[t][d];
#pragma unroll
      for (int t = 0; t < 32; ++t) r2[t] = geT[32 + t] * (float)Kl[32 + t][d];
    } else {
      const int j = tid - 128;
      const float* vsrc = act + ((size_t)b * T_ + t0) * CD_ + 2 * KD_ + h * HD_ + j;
#pragma unroll
      for (int t = 0; t < 32; ++t) r1[t] = bts[t] * vsrc[(size_t)t * CD_];
#pragma unroll
      for (int t = 0; t < 32; ++t) r2[t] = bts[32 + t] * vsrc[(size_t)(32 + t) * CD_];
    }
    float u1[32];
#pragma unroll
    for (int j = 0; j < 32; ++j) {
      float a = r1[j];
#pragma unroll
      for (int i = 0; i < j; ++i) a += (float)AbL[j][i] * u1[i];
      u1[j] = a;
      Xl[j][tid] = (__bf16)a;
    }
#pragma unroll
    for (int t2 = 0; t2 < 32; ++t2) {
      float a = r2[t2];
#pragma unroll
      for (int i = 0; i < 32; ++i) a += (float)AbL[32 + t2][i] * u1[i];
      r2[t2] = a;
    }
    float u2[32];
#pragma unroll
    for (int j = 0; j < 32; ++j) {
      float a = r2[j];
#pragma unroll
      for (int i = 0; i < j; ++i) a += (float)AbH[j][i] * u2[i];
      u2[j] = a;
      Xl[32 + j][tid] = (__bf16)a;
    }
  }
  __syncthreads();

  // Wk copy (negated), row-major [t][136]
#pragma unroll
  for (int kck = 0; kck < 4; ++kck) {
    const int q = tid + kck * 256;             // 0..1023
    const int t = q >> 4, d0 = (q & 15) * 8;
    uint4 v = *(const uint4*)&Xl[t][d0];
    v.x ^= 0x80008000u; v.y ^= 0x80008000u; v.z ^= 0x80008000u; v.w ^= 0x80008000u;
    *(uint4*)(void*)(WkG + bhc * (64 * 136) + (size_t)t * 136 + d0) = v;
  }
  // Uloc^T store: UlT[e][t], stride 72 (mirrors kTG pattern)
  {
    const int e = tid >> 1, t8 = (tid & 1) * 32;
#pragma unroll
    for (int i8 = 0; i8 < 4; ++i8) {
      bf16x8 tmp;
#pragma unroll
      for (int jj = 0; jj < 8; ++jj) tmp[jj] = Xl[t8 + i8 * 8 + jj][128 + e];
      *(bf16x8*)(void*)(UlT + bhc * (128 * 72) + (size_t)e * 72 + t8 + i8 * 8) = tmp;
    }
  }
}

// ---------------------------------------------------------------------------
// scan body: sequential inter-chunk recurrence, e-sliced. sb in [0,64):
// sb = (b*16+h)*2 + eh, eh = e-half (64 wide). 512 threads, 8 waves:
// wave w: wt = w&3 (t-tile), jh = w>>2 (e-tile half for u/o);
//         etw = w>>1, dtb = (w&1)*4 (S-tile ownership).
// ---------------------------------------------------------------------------
__device__ __forceinline__ void scan_body(
    const float* __restrict__ act,
    const ushort_t* __restrict__ WkG, const ushort_t* __restrict__ UlT,
    const ushort_t* __restrict__ PmG, const ushort_t* __restrict__ kTG,
    const float* __restrict__ gtG, float* __restrict__ ob,
    int sb, char* smem) {
  const int eh = sb & 1, wg = sb >> 1;
  const int h = wg & 15, b = wg >> 4, hq = h >> 1;
  const int e0 = eh * 64;
  const int tid = threadIdx.x, lane = tid & 63, wave = tid >> 6;
  const int wt = wave & 3, jh = wave >> 2;
  const int l15 = lane & 15, kcol0 = (lane >> 4) * 8, rrow = (lane >> 4) * 4;
  const int etw = wave >> 1, dtb = (wave & 1) * 4;

  __bf16 (*S16)[136] = (__bf16(*)[136])smem;            // [64][136] 17408 B
  __bf16 (*uTl)[72]  = (__bf16(*)[72])(smem + 17408);   // [64][72]   9216 B
  float* gam = (float*)(smem + 26624);
  float* esc = gam + 64;

  f32x4 s_acc[4] = {};   // dt_local 0..3: S^T[16*etw+rrow+r][(dtb+dl)*16+l15]

  for (int c = 0; c < 32; ++c) {
    const size_t bhc = (size_t)wg * 32 + c;
    const int t0g = c * 64;
    const ushort_t* WkR = WkG + bhc * (64 * 136);
    const ushort_t* UlR = UlT + bhc * (128 * 72) + (size_t)e0 * 72;
    const ushort_t* PmR = PmG + bhc * 4608;
    const ushort_t* kTR = kTG + (((size_t)b * 8 + hq) * 32 + c) * (128 * 72);

    if (tid < 64) {
      const float gCv = gtG[bhc * 64 + 63];
      const float gv = gtG[bhc * 64 + tid];
      gam[tid] = __expf(gv);
      esc[tid] = __expf(gCv - gv);
    }
    // S16 <- bf16(s_acc)
#pragma unroll
    for (int dl = 0; dl < 4; ++dl)
#pragma unroll
      for (int r = 0; r < 4; ++r)
        S16[etw * 16 + rrow + r][(dtb + dl) * 16 + l15] = (__bf16)s_acc[dl][r];
    __syncthreads();

    // u-phase: u[t][e] = Uloc[t][e] + (-Wk)@S ; write uTl[e][t]
    bf16x8 wa[4];
#pragma unroll
    for (int kk = 0; kk < 4; ++kk)
      wa[kk] = *(const bf16x8*)(const void*)(WkR + (size_t)(16 * wt + l15) * 136 + kk * 32 + kcol0);
    f32x4 au0 = {}, au1 = {};
#pragma unroll
    for (int kk = 0; kk < 4; ++kk) {
      bf16x8 sb0 = *(const bf16x8*)&S16[(jh * 2 + 0) * 16 + l15][kk * 32 + kcol0];
      bf16x8 sb1 = *(const bf16x8*)&S16[(jh * 2 + 1) * 16 + l15][kk * 32 + kcol0];
      au0 = __builtin_amdgcn_mfma_f32_16x16x32_bf16(wa[kk], sb0, au0, 0, 0, 0);
      au1 = __builtin_amdgcn_mfma_f32_16x16x32_bf16(wa[kk], sb1, au1, 0, 0, 0);
    }
    {
      short4v uv0 = *(const short4v*)(const void*)(UlR + (size_t)((jh * 2 + 0) * 16 + l15) * 72 + wt * 16 + rrow);
      short4v uv1 = *(const short4v*)(const void*)(UlR + (size_t)((jh * 2 + 1) * 16 + l15) * 72 + wt * 16 + rrow);
#pragma unroll
      for (int r = 0; r < 4; ++r) {
        uTl[(jh * 2 + 0) * 16 + l15][wt * 16 + rrow + r] = (__bf16)(au0[r] + b2f((ushort_t)uv0[r]));
        uTl[(jh * 2 + 1) * 16 + l15][wt * 16 + rrow + r] = (__bf16)(au1[r] + b2f((ushort_t)uv1[r]));
      }
    }
    __syncthreads();

    // o-phase: o = gam*Q@S + Pm@u
    f32x4 qs0 = {}, qs1 = {}, o20 = {}, o21 = {};
#pragma unroll
    for (int kk = 0; kk < 4; ++kk) {
      bf16x8 qa = cvt8f(act + ((size_t)b * T_ + t0g + 16 * wt + l15) * CD_ + hq * HD_ + kk * 32 + kcol0);
      bf16x8 sb0 = *(const bf16x8*)&S16[(jh * 2 + 0) * 16 + l15][kk * 32 + kcol0];
      bf16x8 sb1 = *(const bf16x8*)&S16[(jh * 2 + 1) * 16 + l15][kk * 32 + kcol0];
      qs0 = __builtin_amdgcn_mfma_f32_16x16x32_bf16(qa, sb0, qs0, 0, 0, 0);
      qs1 = __builtin_amdgcn_mfma_f32_16x16x32_bf16(qa, sb1, qs1, 0, 0, 0);
    }
#pragma unroll
    for (int ks = 0; ks < 2; ++ks) {
      bf16x8 pa = *(const bf16x8*)(const void*)(PmR + (size_t)(16 * wt + l15) * 72 + ks * 32 + kcol0);
      bf16x8 ub0 = *(const bf16x8*)&uTl[(jh * 2 + 0) * 16 + l15][ks * 32 + kcol0];
      bf16x8 ub1 = *(const bf16x8*)&uTl[(jh * 2 + 1) * 16 + l15][ks * 32 + kcol0];
      o20 = __builtin_amdgcn_mfma_f32_16x16x32_bf16(pa, ub0, o20, 0, 0, 0);
      o21 = __builtin_amdgcn_mfma_f32_16x16x32_bf16(pa, ub1, o21, 0, 0, 0);
    }
#pragma unroll
    for (int r = 0; r < 4; ++r) {
      const int t = 16 * wt + rrow + r;
      const size_t orow = (((size_t)b * T_ + t0g + t) * NV_ + h) * HD_ + e0;
      ob[orow + (jh * 2 + 0) * 16 + l15] = gam[t] * qs0[r] + o20[r];
      ob[orow + (jh * 2 + 1) * 16 + l15] = gam[t] * qs1[r] + o21[r];
    }

    // S-update: S^T[e][d] = gam[63]*S + sum_s esc[s]*u[s][e]*K[s][d]
    const float gCe = gam[63];
#pragma unroll
    for (int dl = 0; dl < 4; ++dl)
#pragma unroll
      for (int r = 0; r < 4; ++r) s_acc[dl][r] *= gCe;
#pragma unroll
    for (int ks = 0; ks < 2; ++ks) {
      bf16x8 raw = *(const bf16x8*)&uTl[16 * etw + l15][ks * 32 + kcol0];
      bf16x8 ua;
#pragma unroll
      for (int e = 0; e < 8; ++e)
        ua[e] = (__bf16)((float)raw[e] * esc[ks * 32 + kcol0 + e]);
#pragma unroll
      for (int dl = 0; dl < 4; ++dl) {
        bf16x8 kb = *(const bf16x8*)(const void*)(kTR + (size_t)((dtb + dl) * 16 + l15) * 72 + ks * 32 + kcol0);
        s_acc[dl] = __builtin_amdgcn_mfma_f32_16x16x32_bf16(ua, kb, s_acc[dl], 0, 0, 0);
      }
    }
    __syncthreads();
  }
}

// ---------------------------------------------------------------------------
// FUSED launch: blocks 0..63 = scan, 64..191 = z-gemm (x@Wz^T) tiles.
// All 192 blocks co-resident (1 block/CU) - no dispatch-order assumption.
// ---------------------------------------------------------------------------
__global__ __launch_bounds__(512, 2)
void k_scan_zgemm(const float* __restrict__ act,
                  const ushort_t* __restrict__ WkG, const ushort_t* __restrict__ UlT,
                  const ushort_t* __restrict__ PmG, const ushort_t* __restrict__ kTG,
                  const float* __restrict__ gtG, float* __restrict__ ob,
                  const ushort_t* __restrict__ xB, const ushort_t* __restrict__ WzB,
                  ushort_t* __restrict__ zbuf) {
  __shared__ alignas(16) char smem[131072];
  if (blockIdx.x < 64)
    scan_body(act, WkG, UlT, PmG, kTG, gtG, ob, blockIdx.x, smem);
  else
    gemm256_body<ushort_t>(xB, WzB, zbuf, B_ * T_, VD_, HID_,
                           blockIdx.x - 64, (ushort_t*)smem);
}

// ---------------------------------------------------------------------------
// Gated RMSNorm: out = (o/rms(o)) * norm_w * silu(z) -> bf16.
// ---------------------------------------------------------------------------
__global__ __launch_bounds__(256)
void k_gate_rms(const float* __restrict__ ob, const ushort_t* __restrict__ z,
                const float* __restrict__ nw, ushort_t* __restrict__ og) {
  const int row  = blockIdx.x * 4 + (threadIdx.x >> 6);
  const int lane = threadIdx.x & 63;
  const float* op = ob + (size_t)row * HD_;
  float2 v = *(const float2*)&op[lane * 2];
  float ss = v.x * v.x + v.y * v.y;
#pragma unroll
  for (int m = 1; m < 64; m <<= 1) ss += __shfl_xor(ss, m);
  const float r = 1.f / sqrtf(ss * (1.f / HD_) + 1e-6f);
  unsigned int zz = *(const unsigned int*)&z[(size_t)row * HD_ + lane * 2];
  float z0 = b2f((ushort_t)(zz & 0xffffu));
  float z1 = b2f((ushort_t)(zz >> 16));
  float2 w = *(const float2*)&nw[lane * 2];
  float g0 = z0 / (1.f + expf(-z0));
  float g1 = z1 / (1.f + expf(-z1));
  unsigned int pack = (unsigned int)f2b(v.x * r * w.x * g0)
                    | ((unsigned int)f2b(v.y * r * w.y * g1) << 16);
  *(unsigned int*)&og[(size_t)row * HD_ + lane * 2] = pack;
}

// ---------------------------------------------------------------------------
extern "C" void kernel_launch(void* const* d_in, const int* in_sizes, int n_in,
                              void* d_out, int out_size, void* d_ws, size_t ws_size,
                              hipStream_t stream) {
  const float* x    = (const float*)d_in[0];
  const float* Wqkv = (const float*)d_in[1];
  const float* Wz   = (const float*)d_in[2];
  const float* Wb   = (const float*)d_in[3];
  const float* Wa   = (const float*)d_in[4];
  const float* cw   = (const float*)d_in[5];
  const float* dtb  = (const float*)d_in[6];
  const float* alog = (const float*)d_in[7];
  const float* nw   = (const float*)d_in[8];
  const float* Wout = (const float*)d_in[9];

  char* p = (char*)d_ws;
  ushort_t* qkv_raw = (ushort_t*)p; p += (size_t)B_ * T_ * CD_ * 2;       // 33.5 MB
  ushort_t* zbuf    = (ushort_t*)p; p += (size_t)B_ * T_ * VD_ * 2;       // 16.8 MB
  char*     actBase = p;
  float*    act     = (float*)p;    p += (size_t)B_ * T_ * CD_ * 4;       // 67.1 MB
  float*    betaB   = (float*)p;    p += (size_t)B_ * T_ * NV_ * 4;
  float*    gBuf    = (float*)p;    p += (size_t)B_ * T_ * NV_ * 4;
  float*    obuf    = (float*)p;    p += (size_t)B_ * T_ * NV_ * HD_ * 4; // 33.5 MB
  ushort_t* WoutB   = (ushort_t*)p; p += (size_t)HID_ * VD_ * 2;          // 8.4 MB
  ushort_t* UlT     = (ushort_t*)p; p += (size_t)1024 * 128 * 72 * 2;     // 18.9 MB
  ushort_t* PmG     = (ushort_t*)p; p += (size_t)1024 * 64 * 72 * 2;      //  9.4 MB
  ushort_t* xB      = (ushort_t*)p; p += (size_t)B_ * T_ * HID_ * 2;      // 16.8 MB (dedicated: read after conv)
  ushort_t* WzB     = (ushort_t*)p; p += (size_t)VD_ * HID_ * 2;          //  8.4 MB (dedicated: read after conv)
  // overlays in qkv_raw region (dead after conv; outg written after scan):
  ushort_t* WkG = qkv_raw;                                                // 17.8 MB
  ushort_t* kTG = (ushort_t*)((char*)qkv_raw + 17825792);                 //  9.4 MB
  float*    gtG = (float*)((char*)qkv_raw + 27262976);                    //  0.26 MB
  // bf16 cast buffer aliased into act region (dead before conv writes act):
  ushort_t* WqkvB = (ushort_t*)(actBase);                                 // 33.5 MB region start
  ushort_t* outg  = qkv_raw;        // reuse after scan

  const int M = B_ * T_;  // 4096

  hipLaunchKernelGGL(k_cast_bf16, dim3(M * HID_ / 4 / 256), dim3(256), 0, stream,
                     x, xB, M * HID_ / 4);
  hipLaunchKernelGGL(k_cast_bf16, dim3(CD_ * HID_ / 4 / 256), dim3(256), 0, stream,
                     Wqkv, WqkvB, CD_ * HID_ / 4);
  hipLaunchKernelGGL(k_cast_bf16, dim3(VD_ * HID_ / 4 / 256), dim3(256), 0, stream,
                     Wz, WzB, VD_ * HID_ / 4);
  hipLaunchKernelGGL(k_cast_bf16, dim3(HID_ * VD_ / 4 / 256), dim3(256), 0, stream,
                     Wout, WoutB, HID_ * VD_ / 4);

  hipLaunchKernelGGL(k_gemm256<ushort_t>, dim3((M / 256) * (CD_ / 256)), dim3(512), 0, stream,
                     xB, WqkvB, qkv_raw, M, CD_, HID_);
  hipLaunchKernelGGL(k_proj_ba, dim3(M), dim3(256), 0, stream,
                     x, Wb, Wa, dtb, alog, betaB, gBuf);
  hipLaunchKernelGGL(k_conv_silu, dim3(M * CD_ / 4 / 256), dim3(256), 0, stream,
                     qkv_raw, cw, act);
  hipLaunchKernelGGL(k_l2norm_qk, dim3(M * 16 / 4), dim3(256), 0, stream, act);
  hipLaunchKernelGGL(k_prep, dim3(B_ * NV_ * 32), dim3(256), 0, stream,
                     act, gBuf, betaB, WkG, UlT, PmG, kTG, gtG);
  hipLaunchKernelGGL(k_scan_zgemm, dim3(64 + (M / 256) * (VD_ / 256)), dim3(512), 0, stream,
                     act, WkG, UlT, PmG, kTG, gtG, obuf, xB, WzB, zbuf);
  hipLaunchKernelGGL(k_gate_rms, dim3(M * NV_ / 4), dim3(256), 0, stream,
                     obuf, zbuf, nw, outg);
  hipLaunchKernelGGL(k_gemm256<float>, dim3((M / 256) * (HID_ / 256)), dim3(512), 0, stream,
                     outg, WoutB, (float*)d_out, M, HID_, VD_);
}